// Round 8
// baseline (897.085 us; speedup 1.0000x reference)
//
#include <hip/hip_runtime.h>

typedef unsigned short u16;
typedef u16 u16x2 __attribute__((ext_vector_type(2)));
typedef u16 u16x4 __attribute__((ext_vector_type(4)));
typedef u16 u16x8 __attribute__((ext_vector_type(8)));
typedef __bf16 bf16x8 __attribute__((ext_vector_type(8)));
typedef float f32x4 __attribute__((ext_vector_type(4)));

#define B_  2
#define N_  16384
#define T_  2048
#define D_  128
#define S_  384
#define NW_ 512
#define WQ_ 32
#define H_  128
#define L_  3
#define NH_ 4
#define NTOK_ 33
#define BN_ (B_*N_)

__device__ __forceinline__ float b2f(u16 u) {
    return __builtin_bit_cast(float, ((unsigned)u) << 16);
}
__device__ __forceinline__ u16 f2b(float f) {
    unsigned x = __builtin_bit_cast(unsigned, f);
    unsigned r = x + 0x7fffu + ((x >> 16) & 1u);   // RNE
    return (u16)(r >> 16);
}
__device__ __forceinline__ float sigf(float x) { return 1.f / (1.f + __expf(-x)); }
__device__ __forceinline__ float ldin(const void* p, size_t i, int f) {
    return f ? ((const float*)p)[i] : b2f(((const u16*)p)[i]);
}

enum { M_STORE = 0, M_CBSG = 1, M_F32 = 2 };

__global__ void sentinel_k(float* out, float v) { if (threadIdx.x == 0) out[0] = v; }

// Detect input storage dtype from tensor `a`. flag=1 -> f32.
__global__ __launch_bounds__(64) void detect_k(const u16* __restrict__ a, int* flag)
{
    int t = threadIdx.x;
    u16 u = a[2 * t];
    int e = (u >> 7) & 0xFF;
    bool inval = (u != 0) && (e < 96 || e > 143);
    unsigned long long m = __ballot(inval);
    if (t == 0) flag[0] = (__popcll(m) >= 6) ? 1 : 0;
}

// ---------------------------------------------------------------------------
// Plain GEMM: C[m,n] = sum_k A[m,k]*W[k,n], W pre-transposed WT[n,k].
// Tile 128x128, BK=64, 4 waves of 64x64. Swapped-operand MFMA (mfma(b,a)):
// lane's 4 acc regs = 4 consecutive n at fixed m -> vectorized epilogue.
// ---------------------------------------------------------------------------
__global__ __launch_bounds__(256) void gemm_k(
    const u16* __restrict__ A, int lda, int asrc,
    const u16* __restrict__ WT, int K,
    u16* __restrict__ C, int ldc,
    float* __restrict__ QF, int mode, const int* __restrict__ dtf)
{
    __shared__ __align__(16) char smem[36864];
    u16 (*As)[72] = (u16(*)[72])smem;
    u16 (*Bs)[72] = (u16(*)[72])(smem + 18432);

    const int tid = threadIdx.x;
    const int m0 = blockIdx.x * 128, n0 = blockIdx.y * 128;
    const int lane = tid & 63, wid = tid >> 6;
    const int wr = (wid >> 1) * 64, wc = (wid & 1) * 64;
    const int lr = lane & 15, lq = lane >> 4;
    const int af32 = (asrc == 1 && dtf) ? dtf[0] : 0;

    f32x4 zero4 = {0.f, 0.f, 0.f, 0.f};
    f32x4 acc[4][4];
#pragma unroll
    for (int i = 0; i < 4; ++i)
#pragma unroll
        for (int j = 0; j < 4; ++j) acc[i][j] = zero4;

    for (int kt = 0; kt < K; kt += 64) {
#pragma unroll
        for (int i = 0; i < 4; ++i) {
            int id = tid + i * 256;
            int r = id >> 3, c = (id & 7) * 8;
            if (af32) {
                const float* Af = (const float*)A;
                size_t ai = (size_t)(m0 + r) * lda + kt + c;
                f32x4 p0 = *(const f32x4*)&Af[ai];
                f32x4 p1 = *(const f32x4*)&Af[ai + 4];
                u16x8 t;
                t[0] = f2b(p0[0]); t[1] = f2b(p0[1]); t[2] = f2b(p0[2]); t[3] = f2b(p0[3]);
                t[4] = f2b(p1[0]); t[5] = f2b(p1[1]); t[6] = f2b(p1[2]); t[7] = f2b(p1[3]);
                *(u16x8*)&As[r][c] = t;
            } else {
                *(u16x8*)&As[r][c] = *(const u16x8*)&A[(size_t)(m0 + r) * lda + kt + c];
            }
            *(u16x8*)&Bs[r][c] = *(const u16x8*)&WT[(size_t)(n0 + r) * K + kt + c];
        }
        __syncthreads();
#pragma unroll
        for (int ks = 0; ks < 2; ++ks) {
            bf16x8 af[4], bfr[4];
#pragma unroll
            for (int t = 0; t < 4; ++t) {
                af[t]  = *(const bf16x8*)&As[wr + t * 16 + lr][ks * 32 + lq * 8];
                bfr[t] = *(const bf16x8*)&Bs[wc + t * 16 + lr][ks * 32 + lq * 8];
            }
#pragma unroll
            for (int mt = 0; mt < 4; ++mt)
#pragma unroll
                for (int nt = 0; nt < 4; ++nt)
                    acc[mt][nt] = __builtin_amdgcn_mfma_f32_16x16x32_bf16(
                        bfr[nt], af[mt], acc[mt][nt], 0, 0, 0);
        }
        __syncthreads();
    }

    const bool sig_half = (n0 >= 128);   // for M_CBSG (cb0 | cs0 pair)
#pragma unroll
    for (int mt = 0; mt < 4; ++mt)
#pragma unroll
        for (int nt = 0; nt < 4; ++nt) {
            int lm = wr + mt * 16 + lr;
            int lnb = wc + nt * 16 + lq * 4;
            int m = m0 + lm;
            size_t o = (size_t)m * ldc + n0 + lnb;
            f32x4 v = acc[mt][nt];
            if (mode == M_STORE) {
                u16x4 t = {f2b(v[0]), f2b(v[1]), f2b(v[2]), f2b(v[3])};
                *(u16x4*)&C[o] = t;
            } else if (mode == M_CBSG) {
                u16x4 t;
#pragma unroll
                for (int r = 0; r < 4; ++r) t[r] = f2b(sig_half ? sigf(v[r]) : v[r]);
                *(u16x4*)&C[o] = t;
            } else {  // M_F32
                *(f32x4*)&QF[o] = v;
            }
        }
}

// ---------------------------------------------------------------------------
// Merged per-layer residual kernel (grid 256, 1 block per 128 rows).
// R8: (1) qf row-state carried in REGISTERS across both residual phases --
// phase-a no longer writes QF, phase-b no longer reads it (-96 MB/iter,
// bit-identical since nothing reads QF between). (2) cn has a dedicated
// persistent LDS buffer, so phase-b's re-stage is gone (-25 MB/iter).
// LDS 106 KB (grid=256 -> 1 block/CU regardless).
// ---------------------------------------------------------------------------
__global__ __launch_bounds__(256) void fres_k(
    const u16* __restrict__ A,          // obuf (128-wide bf16)
    const u16* __restrict__ cnb,
    const u16* __restrict__ WT1,        // Wo^T [128][128]
    const u16* __restrict__ WEa, const u16* __restrict__ WSa, const u16* __restrict__ WBa,
    const u16* __restrict__ W12,        // interleaved [512][128]
    const u16* __restrict__ W3T,        // [128][256]
    const u16* __restrict__ WEb, const u16* __restrict__ WSb, const u16* __restrict__ WBb,
    float* __restrict__ QF,
    const u16* __restrict__ WT4, u16* __restrict__ C4,   // Wqkv(l+1)^T, proj
    int last)
{
    __shared__ __align__(16) char smem[108544];
    u16 (*Cs)[136] = (u16(*)[136])smem;                   // cn tile (persistent)
    u16 (*Hs)[136] = (u16(*)[136])(smem + 34816);         // LN output
    u16 (*Bw)[136] = (u16(*)[136])(smem + 69632);         // pre-gemm weight tile
    u16 (*As)[72]  = (u16(*)[72])(smem + 69632);          // stage-1 A
    u16 (*Bs)[72]  = (u16(*)[72])(smem + 69632 + 18432);  // stage-1 B
    u16 (*Bs2)[72] = (u16(*)[72])(smem + 69632);          // chunk B tiles
    u16 (*Ut)[72]  = (u16(*)[72])(smem + 69632 + 18432);  // fused silu tile
    float* LNp = (float*)(smem + 106496);                 // [4][64][2]

    const int tid = threadIdx.x;
    const int m0 = blockIdx.x * 128;
    const int lane = tid & 63, wid = tid >> 6;
    const int wr = (wid >> 1) * 64, wc = (wid & 1) * 64;
    const int lr = lane & 15, lq = lane >> 4;
    f32x4 zero4 = {0.f, 0.f, 0.f, 0.f};

    u16x4 e1q[4][4], sgq[4][4], cbq[4][4];
    f32x4 q[4][4];

    auto pregemm = [&](const u16* Wp, int dosig, u16x4 (*out)[4]) {
#pragma unroll
        for (int i = 0; i < 8; ++i) {
            int id = tid + i * 256;
            int r = id >> 4, c = (id & 15) * 8;
            *(u16x8*)&Bw[r][c] = *(const u16x8*)&Wp[(size_t)r * 128 + c];
        }
        __syncthreads();
        f32x4 pacc[4][4];
#pragma unroll
        for (int i = 0; i < 4; ++i)
#pragma unroll
            for (int j = 0; j < 4; ++j) pacc[i][j] = zero4;
#pragma unroll
        for (int kk = 0; kk < 4; ++kk) {
            bf16x8 af[4], bfr[4];
#pragma unroll
            for (int t = 0; t < 4; ++t) {
                af[t]  = *(const bf16x8*)&Cs[wr + t * 16 + lr][kk * 32 + lq * 8];
                bfr[t] = *(const bf16x8*)&Bw[wc + t * 16 + lr][kk * 32 + lq * 8];
            }
#pragma unroll
            for (int mt = 0; mt < 4; ++mt)
#pragma unroll
                for (int nt = 0; nt < 4; ++nt)
                    pacc[mt][nt] = __builtin_amdgcn_mfma_f32_16x16x32_bf16(
                        bfr[nt], af[mt], pacc[mt][nt], 0, 0, 0);
        }
        __syncthreads();
#pragma unroll
        for (int mt = 0; mt < 4; ++mt)
#pragma unroll
            for (int nt = 0; nt < 4; ++nt) {
                u16x4 t;
#pragma unroll
                for (int r = 0; r < 4; ++r) {
                    float v = pacc[mt][nt][r];
                    t[r] = f2b(dosig ? sigf(v) : v);
                }
                out[mt][nt] = t;
            }
    };

    auto lnmix = [&]() {
        float s0[4], sq0[4];
#pragma unroll
        for (int mt = 0; mt < 4; ++mt) {
            float s = 0.f, sq = 0.f;
#pragma unroll
            for (int nt = 0; nt < 4; ++nt)
#pragma unroll
                for (int r = 0; r < 4; ++r) {
                    float v = q[mt][nt][r];
                    s += v; sq += v * v;
                }
            s  += __shfl_xor(s, 16, 64);  sq += __shfl_xor(sq, 16, 64);
            s  += __shfl_xor(s, 32, 64);  sq += __shfl_xor(sq, 32, 64);
            s0[mt] = s; sq0[mt] = sq;
        }
        if (lq == 0) {
#pragma unroll
            for (int mt = 0; mt < 4; ++mt) {
                int row = mt * 16 + lr;
                LNp[wid * 128 + row * 2 + 0] = s0[mt];
                LNp[wid * 128 + row * 2 + 1] = sq0[mt];
            }
        }
        __syncthreads();
#pragma unroll
        for (int mt = 0; mt < 4; ++mt) {
            int row = mt * 16 + lr;
            int w0 = wid & 2;
            float S  = LNp[w0 * 128 + row * 2 + 0] + LNp[(w0 + 1) * 128 + row * 2 + 0];
            float SQ = LNp[w0 * 128 + row * 2 + 1] + LNp[(w0 + 1) * 128 + row * 2 + 1];
            float mu = S * (1.f / 128.f);
            float var = SQ * (1.f / 128.f) - mu * mu;
            float inv = rsqrtf(fmaxf(var, 0.f) + 1e-5f);
            int lm = wr + mt * 16 + lr;
#pragma unroll
            for (int nt = 0; nt < 4; ++nt) {
                u16x4 sg = sgq[mt][nt], cb = cbq[mt][nt];
                u16x4 hv;
#pragma unroll
                for (int r = 0; r < 4; ++r)
                    hv[r] = f2b((q[mt][nt][r] - mu) * inv * b2f(sg[r]) + b2f(cb[r]));
                *(u16x4*)&Hs[lm][wc + nt * 16 + lq * 4] = hv;
            }
        }
    };

    // ---- phase a ----
#pragma unroll
    for (int i = 0; i < 8; ++i) {            // stage cn once (persistent)
        int id = tid + i * 256;
        int r = id >> 4, c = (id & 15) * 8;
        *(u16x8*)&Cs[r][c] = *(const u16x8*)&cnb[(size_t)(m0 + r) * 128 + c];
    }
    pregemm(WEa, 1, e1q);
    pregemm(WSa, 1, sgq);
    pregemm(WBa, 0, cbq);

    f32x4 acc[4][4];
#pragma unroll
    for (int i = 0; i < 4; ++i)
#pragma unroll
        for (int j = 0; j < 4; ++j) acc[i][j] = zero4;
    for (int kt = 0; kt < 128; kt += 64) {
#pragma unroll
        for (int i = 0; i < 4; ++i) {
            int id = tid + i * 256;
            int r = id >> 3, c = (id & 7) * 8;
            *(u16x8*)&As[r][c] = *(const u16x8*)&A[(size_t)(m0 + r) * 128 + kt + c];
            *(u16x8*)&Bs[r][c] = *(const u16x8*)&WT1[(size_t)r * 128 + kt + c];
        }
        __syncthreads();
#pragma unroll
        for (int ks = 0; ks < 2; ++ks) {
            bf16x8 af[4], bfr[4];
#pragma unroll
            for (int t = 0; t < 4; ++t) {
                af[t]  = *(const bf16x8*)&As[wr + t * 16 + lr][ks * 32 + lq * 8];
                bfr[t] = *(const bf16x8*)&Bs[wc + t * 16 + lr][ks * 32 + lq * 8];
            }
#pragma unroll
            for (int mt = 0; mt < 4; ++mt)
#pragma unroll
                for (int nt = 0; nt < 4; ++nt)
                    acc[mt][nt] = __builtin_amdgcn_mfma_f32_16x16x32_bf16(
                        bfr[nt], af[mt], acc[mt][nt], 0, 0, 0);
        }
        __syncthreads();
    }
    // residual a: q = QF + E1a*acc  (register-carried; NO QF write here)
#pragma unroll
    for (int mt = 0; mt < 4; ++mt)
#pragma unroll
        for (int nt = 0; nt < 4; ++nt) {
            int m = m0 + wr + mt * 16 + lr;
            int nb = wc + nt * 16 + lq * 4;
            size_t o = (size_t)m * 128 + nb;
            f32x4 qv = *(const f32x4*)&QF[o];
            u16x4 e = e1q[mt][nt];
#pragma unroll
            for (int r = 0; r < 4; ++r) qv[r] += b2f(e[r]) * acc[mt][nt][r];
            q[mt][nt] = qv;
        }
    lnmix();   // Hs = hcur-a

    // ---- FFN chunks: u12 in LDS only ----
    f32x4 acc3[4][4];
#pragma unroll
    for (int i = 0; i < 4; ++i)
#pragma unroll
        for (int j = 0; j < 4; ++j) acc3[i][j] = zero4;

    for (int ch = 0; ch < 4; ++ch) {
        f32x4 acc2[4][4];
#pragma unroll
        for (int i = 0; i < 4; ++i)
#pragma unroll
            for (int j = 0; j < 4; ++j) acc2[i][j] = zero4;
#pragma unroll
        for (int kt2 = 0; kt2 < 128; kt2 += 64) {
            __syncthreads();
#pragma unroll
            for (int i = 0; i < 4; ++i) {
                int id = tid + i * 256;
                int r = id >> 3, c = (id & 7) * 8;
                *(u16x8*)&Bs2[r][c] =
                    *(const u16x8*)&W12[(size_t)(ch * 128 + r) * 128 + kt2 + c];
            }
            __syncthreads();
#pragma unroll
            for (int ks = 0; ks < 2; ++ks) {
                bf16x8 af[4], bfr[4];
#pragma unroll
                for (int t = 0; t < 4; ++t) {
                    af[t]  = *(const bf16x8*)&Hs[wr + t * 16 + lr][kt2 + ks * 32 + lq * 8];
                    bfr[t] = *(const bf16x8*)&Bs2[wc + t * 16 + lr][ks * 32 + lq * 8];
                }
#pragma unroll
                for (int mt = 0; mt < 4; ++mt)
#pragma unroll
                    for (int nt = 0; nt < 4; ++nt)
                        acc2[mt][nt] = __builtin_amdgcn_mfma_f32_16x16x32_bf16(
                            bfr[nt], af[mt], acc2[mt][nt], 0, 0, 0);
            }
        }
        // silu pairs (even n = W1, odd n = W2 of same fused col); round to
        // bf16 first so the math matches the old u12 HBM path bit-for-bit.
#pragma unroll
        for (int mt = 0; mt < 4; ++mt)
#pragma unroll
            for (int nt = 0; nt < 4; ++nt) {
                f32x4 v = acc2[mt][nt];
                float a0 = b2f(f2b(v[0])), a1 = b2f(f2b(v[1]));
                float a2 = b2f(f2b(v[2])), a3 = b2f(f2b(v[3]));
                u16x2 t;
                t[0] = f2b(a0 * sigf(a0) * a1);
                t[1] = f2b(a2 * sigf(a2) * a3);
                int lm = wr + mt * 16 + lr;
                int fc = (wc >> 1) + nt * 8 + lq * 2;
                *(u16x2*)&Ut[lm][fc] = t;
            }
        __syncthreads();
#pragma unroll
        for (int i = 0; i < 4; ++i) {
            int id = tid + i * 256;
            int r = id >> 3, c = (id & 7) * 8;
            *(u16x8*)&Bs2[r][c] = *(const u16x8*)&W3T[(size_t)r * 256 + ch * 64 + c];
        }
        __syncthreads();
#pragma unroll
        for (int ks = 0; ks < 2; ++ks) {
            bf16x8 af[4], bfr[4];
#pragma unroll
            for (int t = 0; t < 4; ++t) {
                af[t]  = *(const bf16x8*)&Ut[wr + t * 16 + lr][ks * 32 + lq * 8];
                bfr[t] = *(const bf16x8*)&Bs2[wc + t * 16 + lr][ks * 32 + lq * 8];
            }
#pragma unroll
            for (int mt = 0; mt < 4; ++mt)
#pragma unroll
                for (int nt = 0; nt < 4; ++nt)
                    acc3[mt][nt] = __builtin_amdgcn_mfma_f32_16x16x32_bf16(
                        bfr[nt], af[mt], acc3[mt][nt], 0, 0, 0);
        }
    }

    // ---- phase b ----
    __syncthreads();
    pregemm(WEb, 1, e1q);
    if (!last) {
        pregemm(WSb, 1, sgq);
        pregemm(WBb, 0, cbq);
    }
    // residual b: q += E1b*acc3; single QF write for the whole layer
#pragma unroll
    for (int mt = 0; mt < 4; ++mt)
#pragma unroll
        for (int nt = 0; nt < 4; ++nt) {
            int m = m0 + wr + mt * 16 + lr;
            int nb = wc + nt * 16 + lq * 4;
            size_t o = (size_t)m * 128 + nb;
            f32x4 qv = q[mt][nt];
            u16x4 e = e1q[mt][nt];
#pragma unroll
            for (int r = 0; r < 4; ++r) qv[r] += b2f(e[r]) * acc3[mt][nt][r];
            *(f32x4*)&QF[o] = qv;
            q[mt][nt] = qv;
        }
    if (last) return;
    lnmix();   // Hs = hcur-b

    for (int nc = 0; nc < 512; nc += 128) {
        f32x4 acc2[4][4];
#pragma unroll
        for (int i = 0; i < 4; ++i)
#pragma unroll
            for (int j = 0; j < 4; ++j) acc2[i][j] = zero4;
#pragma unroll
        for (int kt2 = 0; kt2 < 128; kt2 += 64) {
            __syncthreads();
#pragma unroll
            for (int i = 0; i < 4; ++i) {
                int id = tid + i * 256;
                int r = id >> 3, c = (id & 7) * 8;
                *(u16x8*)&Bs2[r][c] =
                    *(const u16x8*)&WT4[(size_t)(nc + r) * 128 + kt2 + c];
            }
            __syncthreads();
#pragma unroll
            for (int ks = 0; ks < 2; ++ks) {
                bf16x8 af[4], bfr[4];
#pragma unroll
                for (int t = 0; t < 4; ++t) {
                    af[t]  = *(const bf16x8*)&Hs[wr + t * 16 + lr][kt2 + ks * 32 + lq * 8];
                    bfr[t] = *(const bf16x8*)&Bs2[wc + t * 16 + lr][ks * 32 + lq * 8];
                }
#pragma unroll
                for (int mt = 0; mt < 4; ++mt)
#pragma unroll
                    for (int nt = 0; nt < 4; ++nt)
                        acc2[mt][nt] = __builtin_amdgcn_mfma_f32_16x16x32_bf16(
                            bfr[nt], af[mt], acc2[mt][nt], 0, 0, 0);
            }
        }
#pragma unroll
        for (int mt = 0; mt < 4; ++mt)
#pragma unroll
            for (int nt = 0; nt < 4; ++nt) {
                int m = m0 + wr + mt * 16 + lr;
                int n = nc + wc + nt * 16 + lq * 4;
                f32x4 v = acc2[mt][nt];
                u16x4 t = {f2b(v[0]), f2b(v[1]), f2b(v[2]), f2b(v[3])};
                *(u16x4*)&C4[(size_t)m * 512 + n] = t;
            }
    }
}

// ---------------------------------------------------------------------------
// Windowed attention: one block per (b,w), one wave per head.
// Pitch-136 + Vt XOR swizzle = bank-conflict-free (see R5). R8: bias is read
// DIRECTLY from the input tensor (dtype via dtf; f32 path double-rounds
// through bf16 to stay bit-identical with the old biasbf copy).
// ---------------------------------------------------------------------------
#define VSWZ(d) ((((d) >> 3) & 7) << 3)
__global__ __launch_bounds__(256) void attn_k(
    const u16* __restrict__ proj,
    const void* __restrict__ bias_in,
    const void* __restrict__ mask,
    const int* __restrict__ key_idx,
    u16* __restrict__ o_out,
    const int* __restrict__ dtf)
{
    __shared__ __align__(16) u16 Ks[128][136];
    __shared__ __align__(16) u16 Vt[128][136];
    const int tid = threadIdx.x;
    const int b = blockIdx.x >> 9, w = blockIdx.x & 511;
    int raw = key_idx[w * 128];
    if ((unsigned)raw > (unsigned)(N_ - H_))
        raw = (int)__builtin_bit_cast(float, raw);
    const int ks0 = raw < 0 ? 0 : (raw > N_ - H_ ? N_ - H_ : raw);
    const int lane = tid & 63, h = tid >> 6;
    const int lr = lane & 15, lq = lane >> 4;
    const int hoff = h * 32;
    const int f = dtf[0];

#pragma unroll
    for (int i = 0; i < 8; ++i) {
        int id = tid + i * 256;
        int r = id >> 4, c = (id & 15) * 8;
        size_t gbase = ((size_t)(b * N_ + ks0 + r)) * 512;
        *(u16x8*)&Ks[r][c] = *(const u16x8*)&proj[gbase + 128 + c];
        u16x8 v = *(const u16x8*)&proj[gbase + 256 + c];
#pragma unroll
        for (int j = 0; j < 8; ++j) {
            int d = c + j;
            Vt[d][r ^ VSWZ(d)] = v[j];
        }
    }
    __syncthreads();

    bf16x8 aq[2];
#pragma unroll
    for (int mt = 0; mt < 2; ++mt) {
        int qa = w * 32 + mt * 16 + lr;
        aq[mt] = *(const bf16x8*)&proj[((size_t)(b * N_ + qa)) * 512 + hoff + lq * 8];
    }
    f32x4 zero4 = {0.f, 0.f, 0.f, 0.f};
    f32x4 s[2][8];
#pragma unroll
    for (int nt = 0; nt < 8; ++nt) {
        bf16x8 bk = *(const bf16x8*)&Ks[nt * 16 + lr][hoff + lq * 8];
        s[0][nt] = __builtin_amdgcn_mfma_f32_16x16x32_bf16(aq[0], bk, zero4, 0, 0, 0);
        s[1][nt] = __builtin_amdgcn_mfma_f32_16x16x32_bf16(aq[1], bk, zero4, 0, 0, 0);
    }

    const float scl = 0.17677669529663687f;
    float mb[8];
#pragma unroll
    for (int nt = 0; nt < 8; ++nt)
        mb[nt] = (1.f - ldin(mask, (size_t)b * N_ + ks0 + nt * 16 + lr, f)) * -1e9f;
    size_t bb = (((size_t)b * 512 + w) * 4 + h) * (size_t)(32 * 128);
#pragma unroll
    for (int mt = 0; mt < 2; ++mt)
#pragma unroll
        for (int nt = 0; nt < 8; ++nt)
#pragma unroll
            for (int r = 0; r < 4; ++r) {
                int qq = mt * 16 + lq * 4 + r;
                int kk = nt * 16 + lr;
                size_t bi = bb + (size_t)qq * 128 + kk;
                float bv = f ? b2f(f2b(((const float*)bias_in)[bi]))
                             : b2f(((const u16*)bias_in)[bi]);
                s[mt][nt][r] = s[mt][nt][r] * scl + bv + mb[nt];
            }

#pragma unroll
    for (int mt = 0; mt < 2; ++mt)
#pragma unroll
        for (int r = 0; r < 4; ++r) {
            float mx = -3.4e38f;
#pragma unroll
            for (int nt = 0; nt < 8; ++nt) mx = fmaxf(mx, s[mt][nt][r]);
#pragma unroll
            for (int off = 1; off < 16; off <<= 1) mx = fmaxf(mx, __shfl_xor(mx, off, 64));
            float sm = 0.f;
#pragma unroll
            for (int nt = 0; nt < 8; ++nt) {
                float p = __expf(s[mt][nt][r] - mx);
                s[mt][nt][r] = p; sm += p;
            }
#pragma unroll
            for (int off = 1; off < 16; off <<= 1) sm += __shfl_xor(sm, off, 64);
            float inv = 1.f / sm;
#pragma unroll
            for (int nt = 0; nt < 8; ++nt) s[mt][nt][r] *= inv;
        }

    __syncthreads();
#pragma unroll
    for (int mt = 0; mt < 2; ++mt)
#pragma unroll
        for (int nt = 0; nt < 8; ++nt)
#pragma unroll
            for (int r = 0; r < 4; ++r)
                Ks[hoff + mt * 16 + lq * 4 + r][nt * 16 + lr] = f2b(s[mt][nt][r]);
    __syncthreads();

    f32x4 o[2][2];
    o[0][0] = zero4; o[0][1] = zero4; o[1][0] = zero4; o[1][1] = zero4;
#pragma unroll
    for (int kst = 0; kst < 4; ++kst) {
        bf16x8 ap[2], bv[2];
#pragma unroll
        for (int mt = 0; mt < 2; ++mt)
            ap[mt] = *(const bf16x8*)&Ks[hoff + mt * 16 + lr][kst * 32 + lq * 8];
#pragma unroll
        for (int nt = 0; nt < 2; ++nt) {
            int d = hoff + nt * 16 + lr;
            bv[nt] = *(const bf16x8*)&Vt[d][(kst * 32 + lq * 8) ^ VSWZ(d)];
        }
#pragma unroll
        for (int mt = 0; mt < 2; ++mt)
#pragma unroll
            for (int nt = 0; nt < 2; ++nt)
                o[mt][nt] = __builtin_amdgcn_mfma_f32_16x16x32_bf16(ap[mt], bv[nt], o[mt][nt], 0, 0, 0);
    }

#pragma unroll
    for (int mt = 0; mt < 2; ++mt)
#pragma unroll
        for (int nt = 0; nt < 2; ++nt)
#pragma unroll
            for (int r = 0; r < 4; ++r) {
                int qa = w * 32 + mt * 16 + lq * 4 + r;
                int d = hoff + nt * 16 + lr;
                size_t gi = ((size_t)(b * N_ + qa)) * 512 + 384 + d;
                float g = sigf(b2f(proj[gi]));
                o_out[((size_t)(b * N_ + qa)) * 128 + d] = f2b(g * o[mt][nt][r]);
            }
}

// ---------------------------------------------------------------------------
// Merged prologue (R8: bias-copy phase removed -- attn reads bias directly):
// blocks [0,8192) LN(c)->cn; [8192,8192+43*12) weight transposes, 64x64
// LDS-tiled. TJob.ilv!=0 writes interleaved output rows (W1/W2 pairing).
// ---------------------------------------------------------------------------
struct TJob { const void* base; int off; int dst; int K; int N; int ilv; };
struct TJobs { TJob j[43]; };
__global__ __launch_bounds__(256) void prologue_k(
    const void* __restrict__ c_in, u16* __restrict__ cn,
    TJobs jobs, u16* __restrict__ wt, const int* __restrict__ dtf)
{
    __shared__ __align__(16) u16 Ls[64][72];   // 72-pitch keeps u16x8 stores 16B-aligned
    int bx = blockIdx.x;
    int f = dtf[0];
    if (bx < 8192) {
        int row = bx * 4 + (threadIdx.x >> 6);
        int l = threadIdx.x & 63;
        size_t base = (size_t)row * 128;
        float a = ldin(c_in, base + l, f), b = ldin(c_in, base + l + 64, f);
        float s = a + b, ss = a * a + b * b;
#pragma unroll
        for (int off = 1; off < 64; off <<= 1) {
            s  += __shfl_xor(s, off, 64);
            ss += __shfl_xor(ss, off, 64);
        }
        float m = s * (1.f / 128.f);
        float v = ss * (1.f / 128.f) - m * m;
        float inv = rsqrtf(fmaxf(v, 0.f) + 1e-5f);
        cn[base + l]      = f2b((a - m) * inv);
        cn[base + l + 64] = f2b((b - m) * inv);
    } else {
        int t = bx - 8192;
        int jidx = t / 12, tidx = t - jidx * 12;
        TJob jb = jobs.j[jidx];
        int ntk = jb.K >> 6, ntn = jb.N >> 6;       // 64x64 tiles
        if (tidx >= ntk * ntn) return;
        int kt = (tidx % ntk) << 6;
        int nt = (tidx / ntk) << 6;
        int r = threadIdx.x >> 3, cc = (threadIdx.x & 7) * 8;
#pragma unroll
        for (int p = 0; p < 2; ++p) {
            int kl = r + p * 32;
            size_t si = (size_t)jb.off + (size_t)(kt + kl) * jb.N + nt + cc;
            u16x8 v;
            if (f) {
                const float* s = (const float*)jb.base;
                f32x4 p0 = *(const f32x4*)&s[si];
                f32x4 p1 = *(const f32x4*)&s[si + 4];
                v[0] = f2b(p0[0]); v[1] = f2b(p0[1]); v[2] = f2b(p0[2]); v[3] = f2b(p0[3]);
                v[4] = f2b(p1[0]); v[5] = f2b(p1[1]); v[6] = f2b(p1[2]); v[7] = f2b(p1[3]);
            } else {
                v = *(const u16x8*)&((const u16*)jb.base)[si];
            }
            *(u16x8*)&Ls[kl][cc] = v;
        }
        __syncthreads();
#pragma unroll
        for (int p = 0; p < 2; ++p) {
            int nl = r + p * 32;
            u16x8 w;
#pragma unroll
            for (int j = 0; j < 8; ++j) w[j] = Ls[cc + j][nl];
            int fcol = nt + nl;
            size_t orow = jb.ilv
                ? (size_t)(((fcol >> 6) << 7) + ((fcol & 63) << 1) + (jb.ilv - 1))
                : (size_t)fcol;
            *(u16x8*)&wt[(size_t)jb.dst + orow * jb.K + kt + cc] = w;
        }
    }
}

// ---------------------------------------------------------------------------
// initq + first LN-mix: qf = q_in + aw[token]; hcur = LN(qf)*cs0 + cb0.
// ---------------------------------------------------------------------------
__global__ __launch_bounds__(256) void initq_ln_k(
    const void* __restrict__ qin, const float* __restrict__ aw,
    float* __restrict__ qf,
    const u16* __restrict__ cs0, const u16* __restrict__ cb0, int sgcbld,
    u16* __restrict__ hcur, const int* __restrict__ dtf)
{
    int an = blockIdx.x * 4 + (threadIdx.x >> 6);
    int l = threadIdx.x & 63;
    int f = dtf[0];
    int b = an >> 14, n = an & 16383, t = n >> 3;
    size_t base = (size_t)an * 128;
    size_t ab = ((size_t)b * T_ + t) * 128;
    float a0 = ldin(qin, base + l, f)      + aw[ab + l];
    float a1 = ldin(qin, base + l + 64, f) + aw[ab + l + 64];
    qf[base + l] = a0; qf[base + l + 64] = a1;
    float s = a0 + a1, ss = a0 * a0 + a1 * a1;
#pragma unroll
    for (int off = 1; off < 64; off <<= 1) {
        s  += __shfl_xor(s, off, 64);
        ss += __shfl_xor(ss, off, 64);
    }
    float m = s * (1.f / 128.f);
    float v = ss * (1.f / 128.f) - m * m;
    float inv = rsqrtf(fmaxf(v, 0.f) + 1e-5f);
    size_t sb = (size_t)an * sgcbld;
    hcur[base + l]      = f2b((a0 - m) * inv * b2f(cs0[sb + l])      + b2f(cb0[sb + l]));
    hcur[base + l + 64] = f2b((a1 - m) * inv * b2f(cs0[sb + l + 64]) + b2f(cb0[sb + l + 64]));
}

// ---------------------------------------------------------------------------
// Merged finals: blocks [0,8192) r_update; [8192,9216) res_type (wave/token).
// ---------------------------------------------------------------------------
__global__ __launch_bounds__(256) void final_k(const float* __restrict__ q,
    const void* __restrict__ ln_g, const void* __restrict__ ln_b,
    const void* __restrict__ Wpos,
    const void* __restrict__ mask, const void* __restrict__ Wres,
    const void* __restrict__ bres,
    float* __restrict__ out1, float* __restrict__ out2,
    const int* __restrict__ dtf)
{
    int f = dtf[0];
    int bx = blockIdx.x;
    if (bx < 8192) {
        int row = bx * 4 + (threadIdx.x >> 6);
        int l = threadIdx.x & 63;
        size_t base = (size_t)row * 128;
        float a = q[base + l], b = q[base + l + 64];
        float s = a + b, ss = a * a + b * b;
#pragma unroll
        for (int off = 1; off < 64; off <<= 1) {
            s  += __shfl_xor(s, off, 64);
            ss += __shfl_xor(ss, off, 64);
        }
        float m = s * (1.f / 128.f);
        float v = ss * (1.f / 128.f) - m * m;
        float inv = rsqrtf(fmaxf(v, 0.f) + 1e-5f);
        float y0 = (a - m) * inv * ldin(ln_g, l, f)      + ldin(ln_b, l, f);
        float y1 = (b - m) * inv * ldin(ln_g, l + 64, f) + ldin(ln_b, l + 64, f);
        float p0 = y0 * ldin(Wpos, l * 3 + 0, f) + y1 * ldin(Wpos, (l + 64) * 3 + 0, f);
        float p1 = y0 * ldin(Wpos, l * 3 + 1, f) + y1 * ldin(Wpos, (l + 64) * 3 + 1, f);
        float p2 = y0 * ldin(Wpos, l * 3 + 2, f) + y1 * ldin(Wpos, (l + 64) * 3 + 2, f);
#pragma unroll
        for (int off = 1; off < 64; off <<= 1) {
            p0 += __shfl_xor(p0, off, 64);
            p1 += __shfl_xor(p1, off, 64);
            p2 += __shfl_xor(p2, off, 64);
        }
        if (l == 0) {
            out1[(size_t)row * 3 + 0] = p0;
            out1[(size_t)row * 3 + 1] = p1;
            out1[(size_t)row * 3 + 2] = p2;
        }
    } else {
        __shared__ float sfeat[4][128];
        int wid = threadIdx.x >> 6, l = threadIdx.x & 63;
        int tok = (bx - 8192) * 4 + wid;
        int b = tok >> 11, t = tok & 2047;
        float a0 = 0.f, a1 = 0.f;
#pragma unroll
        for (int i = 0; i < 8; ++i) {
            size_t an = (size_t)b * N_ + t * 8 + i;
            float mk = ldin(mask, an, f);
            a0 += q[an * 128 + l] * mk;
            a1 += q[an * 128 + l + 64] * mk;
        }
        sfeat[wid][l] = a0; sfeat[wid][l + 64] = a1;
        __builtin_amdgcn_s_waitcnt(0);  // wave-local LDS visibility
        if (l < NTOK_) {
            float r = ldin(bres, l, f);
            for (int d = 0; d < 128; ++d) r += sfeat[wid][d] * ldin(Wres, d * NTOK_ + l, f);
            out2[(size_t)tok * NTOK_ + l] = r;
        }
    }
}

// ---------------------------------------------------------------------------
// Workspace layout (bytes), ws = 1 GiB:
//   wt      : 0           weight arena (flag int at 2,088,960)
//   qf      : 2,097,152    f32 BN x 128
//   cn      : 18,874,368   bf16
//   cnprojS : 60,817,408   bf16 BN x 256 [cb0 | cs0]
//   hcur    : 211,812,352  bf16 (layer-0 attn input only)
//   proj    : 220,200,960  bf16 BN x 512
//   obuf    : 253,755,392  bf16
//   aw      : 262,144,000  f32 (prologue only)
// ---------------------------------------------------------------------------
extern "C" void kernel_launch(void* const* d_in, const int* in_sizes, int n_in,
                              void* d_out, int out_size, void* d_ws, size_t ws_size,
                              hipStream_t stream)
{
    (void)out_size;
    float* out = (float*)d_out;
    const size_t WS_NEED = 295698432;

    static const int EXP_SZ[27] = {
        1572864, 4194304, 4194304, 16777216, 67108864, 32768, 65536,
        49152, 49152, 49152, 49152, 49152, 49152,
        49152, 49152, 49152, 49152, 49152, 49152,
        98304, 98304, 98304, 128, 128, 384, 4224, 33 };
    int bad = -1;
    int ncheck = n_in < 27 ? n_in : 27;
    for (int i = 0; i < ncheck; ++i)
        if (in_sizes[i] != EXP_SZ[i]) { bad = i; break; }
    if (bad >= 0) { sentinel_k<<<1, 64, 0, stream>>>(out, 256.0f * (bad + 1)); return; }
    if (n_in < 27) { sentinel_k<<<1, 64, 0, stream>>>(out, 8192.0f); return; }
    if (ws_size < WS_NEED) { sentinel_k<<<1, 64, 0, stream>>>(out, 12288.0f); return; }

    const void* a_in    = d_in[0];
    const void* q_in    = d_in[1];
    const void* c_in    = d_in[2];
    const void* bias_in = d_in[3];
    const void* mask_in = d_in[5];
    const int*  kidx    = (const int*)d_in[6];
    const void* a2q  = d_in[7];
    const void* Wq   = d_in[8];
    const void* Wk   = d_in[9];
    const void* Wv   = d_in[10];
    const void* Wg   = d_in[11];
    const void* Wo   = d_in[12];
    const void* Wcs  = d_in[13];
    const void* Wcb  = d_in[14];
    const void* Wog  = d_in[15];
    const void* Wcs2 = d_in[16];
    const void* Wcb2 = d_in[17];
    const void* Wog2 = d_in[18];
    const void* W1   = d_in[19];
    const void* W2   = d_in[20];
    const void* W3   = d_in[21];
    const void* ln_g = d_in[22];
    const void* ln_b = d_in[23];
    const void* Wpos = d_in[24];
    const void* Wres = d_in[25];
    const void* bres = d_in[26];

    char* ws = (char*)d_ws;
    u16*   wt      = (u16*)ws;
    int*   flag    = (int*)(ws + 2088960);
    float* qf      = (float*)(ws + 2097152);
    u16*   cn      = (u16*)(ws + 18874368);
    u16*   cnprojS = (u16*)(ws + 60817408);
    u16*   hcur    = (u16*)(ws + 211812352);
    u16*   proj    = (u16*)(ws + 220200960);
    u16*   obuf    = (u16*)(ws + 253755392);
    float* aw      = (float*)(ws + 262144000);

    detect_k<<<1, 64, 0, stream>>>((const u16*)a_in, flag);

    // weight arena (elements):
    //   0..196608       Wq|Wk|Wv|Wg per layer (l*65536)
    //   196608 cb0 | 212992 cs0
    //   229376 og[l] | 278528 cs2[l] | 327680 cb2[l] | 376832 og2[l]
    //   425984 cs[1],cs[2] | 458752 cb[1],cb[2]
    //   491520 w12 INTERLEAVED arena | 688128 W3 | 786432 a2q | 835584 Wo
    TJobs jobs; int nj = 0;
    for (int l = 0; l < 3; ++l) {
        jobs.j[nj++] = {Wq,   l * 16384, l * 65536 + 0,     128, 128, 0};
        jobs.j[nj++] = {Wk,   l * 16384, l * 65536 + 16384, 128, 128, 0};
        jobs.j[nj++] = {Wv,   l * 16384, l * 65536 + 32768, 128, 128, 0};
        jobs.j[nj++] = {Wg,   l * 16384, l * 65536 + 49152, 128, 128, 0};
        jobs.j[nj++] = {Wog,  l * 16384, 229376 + l * 16384, 128, 128, 0};
        jobs.j[nj++] = {Wcs2, l * 16384, 278528 + l * 16384, 128, 128, 0};
        jobs.j[nj++] = {Wcb2, l * 16384, 327680 + l * 16384, 128, 128, 0};
        jobs.j[nj++] = {Wog2, l * 16384, 376832 + l * 16384, 128, 128, 0};
        jobs.j[nj++] = {W1,   l * 32768, 491520 + l * 65536, 128, 256, 1};
        jobs.j[nj++] = {W2,   l * 32768, 491520 + l * 65536, 128, 256, 2};
        jobs.j[nj++] = {W3,   l * 32768, 688128 + l * 32768, 256, 128, 0};
        jobs.j[nj++] = {Wo,   l * 16384, 835584 + l * 16384, 128, 128, 0};
    }
    jobs.j[nj++] = {Wcb, 0,     196608, 128, 128, 0};
    jobs.j[nj++] = {Wcs, 0,     212992, 128, 128, 0};
    jobs.j[nj++] = {Wcs, 16384, 425984, 128, 128, 0};
    jobs.j[nj++] = {Wcs, 32768, 442368, 128, 128, 0};
    jobs.j[nj++] = {Wcb, 16384, 458752, 128, 128, 0};
    jobs.j[nj++] = {Wcb, 32768, 475136, 128, 128, 0};
    jobs.j[nj++] = {a2q, 0,     786432, 384, 128, 0};

    prologue_k<<<8192 + 43 * 12, 256, 0, stream>>>(c_in, cn, jobs, wt, flag);
    // aw = a @ a2q (M=4096, K=384, asrc=1)
    gemm_k<<<dim3(32, 1), 256, 0, stream>>>(
        (const u16*)a_in, S_, 1, wt + 786432, S_, nullptr, D_, aw, M_F32, flag);
    // cnprojS = [cb0 | sig(cs0)]
    gemm_k<<<dim3(256, 2), 256, 0, stream>>>(
        cn, D_, 0, wt + 196608, D_, cnprojS, 256, nullptr, M_CBSG, nullptr);
    // qf init + layer-0 attention-half hcur
    initq_ln_k<<<8192, 256, 0, stream>>>(q_in, aw, qf,
        cnprojS + 128, cnprojS + 0, 256, hcur, flag);

    // layer-0 attention projections
    gemm_k<<<dim3(256, 4), 256, 0, stream>>>(
        hcur, D_, 0, wt + 0, D_, proj, 512, nullptr, M_STORE, nullptr);

    for (int l = 0; l < 3; ++l) {
        const u16* wt_proj_n = wt + (l + 1) * 65536;
        const u16* wt_w12  = wt + 491520 + l * 65536;
        const u16* wt_w3   = wt + 688128 + l * 32768;
        const u16* wt_wo   = wt + 835584 + l * 16384;
        const u16* wt_og   = wt + 229376 + l * 16384;
        const u16* wt_cs2  = wt + 278528 + l * 16384;
        const u16* wt_cb2  = wt + 327680 + l * 16384;
        const u16* wt_og2  = wt + 376832 + l * 16384;
        const u16* wt_cs_n = wt + 425984 + l * 16384;   // Wcs[l+1] (l<2)
        const u16* wt_cb_n = wt + 458752 + l * 16384;   // Wcb[l+1] (l<2)

        attn_k<<<1024, 256, 0, stream>>>(proj, bias_in, mask_in, kidx, obuf, flag);
        // one merged kernel per layer: Wo-residual + LN + FFN (u12 in LDS) +
        // W3-residual + LN + next-layer proj; qf row-state register-carried
        fres_k<<<256, 256, 0, stream>>>(
            obuf, cn, wt_wo, wt_og, wt_cs2, wt_cb2,
            wt_w12, wt_w3, wt_og2,
            l < 2 ? wt_cs_n : nullptr, l < 2 ? wt_cb_n : nullptr,
            qf,
            l < 2 ? wt_proj_n : nullptr, proj, l == 2 ? 1 : 0);
    }

    final_k<<<9216, 256, 0, stream>>>(qf, ln_g, ln_b, Wpos, mask_in, Wres, bres,
                                      out, out + (size_t)BN_ * 3, flag);
}

// Round 9
// 894.779 us; speedup vs baseline: 1.0026x; 1.0026x over previous
//
#include <hip/hip_runtime.h>

typedef unsigned short u16;
typedef u16 u16x2 __attribute__((ext_vector_type(2)));
typedef u16 u16x4 __attribute__((ext_vector_type(4)));
typedef u16 u16x8 __attribute__((ext_vector_type(8)));
typedef __bf16 bf16x8 __attribute__((ext_vector_type(8)));
typedef float f32x4 __attribute__((ext_vector_type(4)));

#define B_  2
#define N_  16384
#define T_  2048
#define D_  128
#define S_  384
#define NW_ 512
#define WQ_ 32
#define H_  128
#define L_  3
#define NH_ 4
#define NTOK_ 33
#define BN_ (B_*N_)

__device__ __forceinline__ float b2f(u16 u) {
    return __builtin_bit_cast(float, ((unsigned)u) << 16);
}
__device__ __forceinline__ u16 f2b(float f) {
    unsigned x = __builtin_bit_cast(unsigned, f);
    unsigned r = x + 0x7fffu + ((x >> 16) & 1u);   // RNE
    return (u16)(r >> 16);
}
__device__ __forceinline__ float sigf(float x) { return 1.f / (1.f + __expf(-x)); }
__device__ __forceinline__ float ldin(const void* p, size_t i, int f) {
    return f ? ((const float*)p)[i] : b2f(((const u16*)p)[i]);
}

enum { M_STORE = 0, M_CBSG = 1, M_F32 = 2 };

__global__ void sentinel_k(float* out, float v) { if (threadIdx.x == 0) out[0] = v; }

// Detect input storage dtype from tensor `a`. flag=1 -> f32.
__global__ __launch_bounds__(64) void detect_k(const u16* __restrict__ a, int* flag)
{
    int t = threadIdx.x;
    u16 u = a[2 * t];
    int e = (u >> 7) & 0xFF;
    bool inval = (u != 0) && (e < 96 || e > 143);
    unsigned long long m = __ballot(inval);
    if (t == 0) flag[0] = (__popcll(m) >= 6) ? 1 : 0;
}

// ---------------------------------------------------------------------------
// Plain GEMM: C[m,n] = sum_k A[m,k]*W[k,n], W pre-transposed WT[n,k].
// Tile 128x128, BK=64, 4 waves of 64x64. Swapped-operand MFMA (mfma(b,a)):
// lane's 4 acc regs = 4 consecutive n at fixed m -> vectorized epilogue.
// ---------------------------------------------------------------------------
__global__ __launch_bounds__(256) void gemm_k(
    const u16* __restrict__ A, int lda, int asrc,
    const u16* __restrict__ WT, int K,
    u16* __restrict__ C, int ldc,
    float* __restrict__ QF, int mode, const int* __restrict__ dtf)
{
    __shared__ __align__(16) char smem[36864];
    u16 (*As)[72] = (u16(*)[72])smem;
    u16 (*Bs)[72] = (u16(*)[72])(smem + 18432);

    const int tid = threadIdx.x;
    const int m0 = blockIdx.x * 128, n0 = blockIdx.y * 128;
    const int lane = tid & 63, wid = tid >> 6;
    const int wr = (wid >> 1) * 64, wc = (wid & 1) * 64;
    const int lr = lane & 15, lq = lane >> 4;
    const int af32 = (asrc == 1 && dtf) ? dtf[0] : 0;

    f32x4 zero4 = {0.f, 0.f, 0.f, 0.f};
    f32x4 acc[4][4];
#pragma unroll
    for (int i = 0; i < 4; ++i)
#pragma unroll
        for (int j = 0; j < 4; ++j) acc[i][j] = zero4;

    for (int kt = 0; kt < K; kt += 64) {
#pragma unroll
        for (int i = 0; i < 4; ++i) {
            int id = tid + i * 256;
            int r = id >> 3, c = (id & 7) * 8;
            if (af32) {
                const float* Af = (const float*)A;
                size_t ai = (size_t)(m0 + r) * lda + kt + c;
                f32x4 p0 = *(const f32x4*)&Af[ai];
                f32x4 p1 = *(const f32x4*)&Af[ai + 4];
                u16x8 t;
                t[0] = f2b(p0[0]); t[1] = f2b(p0[1]); t[2] = f2b(p0[2]); t[3] = f2b(p0[3]);
                t[4] = f2b(p1[0]); t[5] = f2b(p1[1]); t[6] = f2b(p1[2]); t[7] = f2b(p1[3]);
                *(u16x8*)&As[r][c] = t;
            } else {
                *(u16x8*)&As[r][c] = *(const u16x8*)&A[(size_t)(m0 + r) * lda + kt + c];
            }
            *(u16x8*)&Bs[r][c] = *(const u16x8*)&WT[(size_t)(n0 + r) * K + kt + c];
        }
        __syncthreads();
#pragma unroll
        for (int ks = 0; ks < 2; ++ks) {
            bf16x8 af[4], bfr[4];
#pragma unroll
            for (int t = 0; t < 4; ++t) {
                af[t]  = *(const bf16x8*)&As[wr + t * 16 + lr][ks * 32 + lq * 8];
                bfr[t] = *(const bf16x8*)&Bs[wc + t * 16 + lr][ks * 32 + lq * 8];
            }
#pragma unroll
            for (int mt = 0; mt < 4; ++mt)
#pragma unroll
                for (int nt = 0; nt < 4; ++nt)
                    acc[mt][nt] = __builtin_amdgcn_mfma_f32_16x16x32_bf16(
                        bfr[nt], af[mt], acc[mt][nt], 0, 0, 0);
        }
        __syncthreads();
    }

    const bool sig_half = (n0 >= 128);   // for M_CBSG (cb0 | cs0 pair)
#pragma unroll
    for (int mt = 0; mt < 4; ++mt)
#pragma unroll
        for (int nt = 0; nt < 4; ++nt) {
            int lm = wr + mt * 16 + lr;
            int lnb = wc + nt * 16 + lq * 4;
            int m = m0 + lm;
            size_t o = (size_t)m * ldc + n0 + lnb;
            f32x4 v = acc[mt][nt];
            if (mode == M_STORE) {
                u16x4 t = {f2b(v[0]), f2b(v[1]), f2b(v[2]), f2b(v[3])};
                *(u16x4*)&C[o] = t;
            } else if (mode == M_CBSG) {
                u16x4 t;
#pragma unroll
                for (int r = 0; r < 4; ++r) t[r] = f2b(sig_half ? sigf(v[r]) : v[r]);
                *(u16x4*)&C[o] = t;
            } else {  // M_F32
                *(f32x4*)&QF[o] = v;
            }
        }
}

// ---------------------------------------------------------------------------
// Merged per-layer residual kernel (grid 256, 1 block per 128 rows).
// R9: reverted R8's qf register-carry -- extending q[4][4] (64 VGPR) live
// across the FFN (which already holds acc3+acc2+staging) caused a spill
// regression (+90us). Phase-a writes QF, phase-b re-reads it, as in R7;
// q is dead during the FFN chunks. KEPT from R8: bias-direct attn read and
// the persistent cn LDS buffer (phase-b re-stage eliminated).
// ---------------------------------------------------------------------------
__global__ __launch_bounds__(256) void fres_k(
    const u16* __restrict__ A,          // obuf (128-wide bf16)
    const u16* __restrict__ cnb,
    const u16* __restrict__ WT1,        // Wo^T [128][128]
    const u16* __restrict__ WEa, const u16* __restrict__ WSa, const u16* __restrict__ WBa,
    const u16* __restrict__ W12,        // interleaved [512][128]
    const u16* __restrict__ W3T,        // [128][256]
    const u16* __restrict__ WEb, const u16* __restrict__ WSb, const u16* __restrict__ WBb,
    float* __restrict__ QF,
    const u16* __restrict__ WT4, u16* __restrict__ C4,   // Wqkv(l+1)^T, proj
    int last)
{
    __shared__ __align__(16) char smem[108544];
    u16 (*Cs)[136] = (u16(*)[136])smem;                   // cn tile (persistent)
    u16 (*Hs)[136] = (u16(*)[136])(smem + 34816);         // LN output
    u16 (*Bw)[136] = (u16(*)[136])(smem + 69632);         // pre-gemm weight tile
    u16 (*As)[72]  = (u16(*)[72])(smem + 69632);          // stage-1 A
    u16 (*Bs)[72]  = (u16(*)[72])(smem + 69632 + 18432);  // stage-1 B
    u16 (*Bs2)[72] = (u16(*)[72])(smem + 69632);          // chunk B tiles
    u16 (*Ut)[72]  = (u16(*)[72])(smem + 69632 + 18432);  // fused silu tile
    float* LNp = (float*)(smem + 106496);                 // [4][64][2]

    const int tid = threadIdx.x;
    const int m0 = blockIdx.x * 128;
    const int lane = tid & 63, wid = tid >> 6;
    const int wr = (wid >> 1) * 64, wc = (wid & 1) * 64;
    const int lr = lane & 15, lq = lane >> 4;
    f32x4 zero4 = {0.f, 0.f, 0.f, 0.f};

    u16x4 e1q[4][4], sgq[4][4], cbq[4][4];
    f32x4 q[4][4];

    auto pregemm = [&](const u16* Wp, int dosig, u16x4 (*out)[4]) {
#pragma unroll
        for (int i = 0; i < 8; ++i) {
            int id = tid + i * 256;
            int r = id >> 4, c = (id & 15) * 8;
            *(u16x8*)&Bw[r][c] = *(const u16x8*)&Wp[(size_t)r * 128 + c];
        }
        __syncthreads();
        f32x4 pacc[4][4];
#pragma unroll
        for (int i = 0; i < 4; ++i)
#pragma unroll
            for (int j = 0; j < 4; ++j) pacc[i][j] = zero4;
#pragma unroll
        for (int kk = 0; kk < 4; ++kk) {
            bf16x8 af[4], bfr[4];
#pragma unroll
            for (int t = 0; t < 4; ++t) {
                af[t]  = *(const bf16x8*)&Cs[wr + t * 16 + lr][kk * 32 + lq * 8];
                bfr[t] = *(const bf16x8*)&Bw[wc + t * 16 + lr][kk * 32 + lq * 8];
            }
#pragma unroll
            for (int mt = 0; mt < 4; ++mt)
#pragma unroll
                for (int nt = 0; nt < 4; ++nt)
                    pacc[mt][nt] = __builtin_amdgcn_mfma_f32_16x16x32_bf16(
                        bfr[nt], af[mt], pacc[mt][nt], 0, 0, 0);
        }
        __syncthreads();
#pragma unroll
        for (int mt = 0; mt < 4; ++mt)
#pragma unroll
            for (int nt = 0; nt < 4; ++nt) {
                u16x4 t;
#pragma unroll
                for (int r = 0; r < 4; ++r) {
                    float v = pacc[mt][nt][r];
                    t[r] = f2b(dosig ? sigf(v) : v);
                }
                out[mt][nt] = t;
            }
    };

    auto lnmix = [&]() {
        float s0[4], sq0[4];
#pragma unroll
        for (int mt = 0; mt < 4; ++mt) {
            float s = 0.f, sq = 0.f;
#pragma unroll
            for (int nt = 0; nt < 4; ++nt)
#pragma unroll
                for (int r = 0; r < 4; ++r) {
                    float v = q[mt][nt][r];
                    s += v; sq += v * v;
                }
            s  += __shfl_xor(s, 16, 64);  sq += __shfl_xor(sq, 16, 64);
            s  += __shfl_xor(s, 32, 64);  sq += __shfl_xor(sq, 32, 64);
            s0[mt] = s; sq0[mt] = sq;
        }
        if (lq == 0) {
#pragma unroll
            for (int mt = 0; mt < 4; ++mt) {
                int row = mt * 16 + lr;
                LNp[wid * 128 + row * 2 + 0] = s0[mt];
                LNp[wid * 128 + row * 2 + 1] = sq0[mt];
            }
        }
        __syncthreads();
#pragma unroll
        for (int mt = 0; mt < 4; ++mt) {
            int row = mt * 16 + lr;
            int w0 = wid & 2;
            float S  = LNp[w0 * 128 + row * 2 + 0] + LNp[(w0 + 1) * 128 + row * 2 + 0];
            float SQ = LNp[w0 * 128 + row * 2 + 1] + LNp[(w0 + 1) * 128 + row * 2 + 1];
            float mu = S * (1.f / 128.f);
            float var = SQ * (1.f / 128.f) - mu * mu;
            float inv = rsqrtf(fmaxf(var, 0.f) + 1e-5f);
            int lm = wr + mt * 16 + lr;
#pragma unroll
            for (int nt = 0; nt < 4; ++nt) {
                u16x4 sg = sgq[mt][nt], cb = cbq[mt][nt];
                u16x4 hv;
#pragma unroll
                for (int r = 0; r < 4; ++r)
                    hv[r] = f2b((q[mt][nt][r] - mu) * inv * b2f(sg[r]) + b2f(cb[r]));
                *(u16x4*)&Hs[lm][wc + nt * 16 + lq * 4] = hv;
            }
        }
    };

    // ---- phase a ----
#pragma unroll
    for (int i = 0; i < 8; ++i) {            // stage cn once (persistent)
        int id = tid + i * 256;
        int r = id >> 4, c = (id & 15) * 8;
        *(u16x8*)&Cs[r][c] = *(const u16x8*)&cnb[(size_t)(m0 + r) * 128 + c];
    }
    pregemm(WEa, 1, e1q);
    pregemm(WSa, 1, sgq);
    pregemm(WBa, 0, cbq);

    f32x4 acc[4][4];
#pragma unroll
    for (int i = 0; i < 4; ++i)
#pragma unroll
        for (int j = 0; j < 4; ++j) acc[i][j] = zero4;
    for (int kt = 0; kt < 128; kt += 64) {
#pragma unroll
        for (int i = 0; i < 4; ++i) {
            int id = tid + i * 256;
            int r = id >> 3, c = (id & 7) * 8;
            *(u16x8*)&As[r][c] = *(const u16x8*)&A[(size_t)(m0 + r) * 128 + kt + c];
            *(u16x8*)&Bs[r][c] = *(const u16x8*)&WT1[(size_t)r * 128 + kt + c];
        }
        __syncthreads();
#pragma unroll
        for (int ks = 0; ks < 2; ++ks) {
            bf16x8 af[4], bfr[4];
#pragma unroll
            for (int t = 0; t < 4; ++t) {
                af[t]  = *(const bf16x8*)&As[wr + t * 16 + lr][ks * 32 + lq * 8];
                bfr[t] = *(const bf16x8*)&Bs[wc + t * 16 + lr][ks * 32 + lq * 8];
            }
#pragma unroll
            for (int mt = 0; mt < 4; ++mt)
#pragma unroll
                for (int nt = 0; nt < 4; ++nt)
                    acc[mt][nt] = __builtin_amdgcn_mfma_f32_16x16x32_bf16(
                        bfr[nt], af[mt], acc[mt][nt], 0, 0, 0);
        }
        __syncthreads();
    }
    // residual a: q = QF + E1a*acc; WRITE QF (R7 semantics -- q dead in FFN)
#pragma unroll
    for (int mt = 0; mt < 4; ++mt)
#pragma unroll
        for (int nt = 0; nt < 4; ++nt) {
            int m = m0 + wr + mt * 16 + lr;
            int nb = wc + nt * 16 + lq * 4;
            size_t o = (size_t)m * 128 + nb;
            f32x4 qv = *(const f32x4*)&QF[o];
            u16x4 e = e1q[mt][nt];
#pragma unroll
            for (int r = 0; r < 4; ++r) qv[r] += b2f(e[r]) * acc[mt][nt][r];
            *(f32x4*)&QF[o] = qv;
            q[mt][nt] = qv;
        }
    lnmix();   // Hs = hcur-a

    // ---- FFN chunks: u12 in LDS only ----
    f32x4 acc3[4][4];
#pragma unroll
    for (int i = 0; i < 4; ++i)
#pragma unroll
        for (int j = 0; j < 4; ++j) acc3[i][j] = zero4;

    for (int ch = 0; ch < 4; ++ch) {
        f32x4 acc2[4][4];
#pragma unroll
        for (int i = 0; i < 4; ++i)
#pragma unroll
            for (int j = 0; j < 4; ++j) acc2[i][j] = zero4;
#pragma unroll
        for (int kt2 = 0; kt2 < 128; kt2 += 64) {
            __syncthreads();
#pragma unroll
            for (int i = 0; i < 4; ++i) {
                int id = tid + i * 256;
                int r = id >> 3, c = (id & 7) * 8;
                *(u16x8*)&Bs2[r][c] =
                    *(const u16x8*)&W12[(size_t)(ch * 128 + r) * 128 + kt2 + c];
            }
            __syncthreads();
#pragma unroll
            for (int ks = 0; ks < 2; ++ks) {
                bf16x8 af[4], bfr[4];
#pragma unroll
                for (int t = 0; t < 4; ++t) {
                    af[t]  = *(const bf16x8*)&Hs[wr + t * 16 + lr][kt2 + ks * 32 + lq * 8];
                    bfr[t] = *(const bf16x8*)&Bs2[wc + t * 16 + lr][ks * 32 + lq * 8];
                }
#pragma unroll
                for (int mt = 0; mt < 4; ++mt)
#pragma unroll
                    for (int nt = 0; nt < 4; ++nt)
                        acc2[mt][nt] = __builtin_amdgcn_mfma_f32_16x16x32_bf16(
                            bfr[nt], af[mt], acc2[mt][nt], 0, 0, 0);
            }
        }
        // silu pairs (even n = W1, odd n = W2 of same fused col); round to
        // bf16 first so the math matches the old u12 HBM path bit-for-bit.
#pragma unroll
        for (int mt = 0; mt < 4; ++mt)
#pragma unroll
            for (int nt = 0; nt < 4; ++nt) {
                f32x4 v = acc2[mt][nt];
                float a0 = b2f(f2b(v[0])), a1 = b2f(f2b(v[1]));
                float a2 = b2f(f2b(v[2])), a3 = b2f(f2b(v[3]));
                u16x2 t;
                t[0] = f2b(a0 * sigf(a0) * a1);
                t[1] = f2b(a2 * sigf(a2) * a3);
                int lm = wr + mt * 16 + lr;
                int fc = (wc >> 1) + nt * 8 + lq * 2;
                *(u16x2*)&Ut[lm][fc] = t;
            }
        __syncthreads();
#pragma unroll
        for (int i = 0; i < 4; ++i) {
            int id = tid + i * 256;
            int r = id >> 3, c = (id & 7) * 8;
            *(u16x8*)&Bs2[r][c] = *(const u16x8*)&W3T[(size_t)r * 256 + ch * 64 + c];
        }
        __syncthreads();
#pragma unroll
        for (int ks = 0; ks < 2; ++ks) {
            bf16x8 af[4], bfr[4];
#pragma unroll
            for (int t = 0; t < 4; ++t) {
                af[t]  = *(const bf16x8*)&Ut[wr + t * 16 + lr][ks * 32 + lq * 8];
                bfr[t] = *(const bf16x8*)&Bs2[wc + t * 16 + lr][ks * 32 + lq * 8];
            }
#pragma unroll
            for (int mt = 0; mt < 4; ++mt)
#pragma unroll
                for (int nt = 0; nt < 4; ++nt)
                    acc3[mt][nt] = __builtin_amdgcn_mfma_f32_16x16x32_bf16(
                        bfr[nt], af[mt], acc3[mt][nt], 0, 0, 0);
        }
    }

    // ---- phase b ----
    __syncthreads();
    pregemm(WEb, 1, e1q);
    if (!last) {
        pregemm(WSb, 1, sgq);
        pregemm(WBb, 0, cbq);
    }
    // residual b: re-read QF (R7 semantics), add E1b*acc3, write QF
#pragma unroll
    for (int mt = 0; mt < 4; ++mt)
#pragma unroll
        for (int nt = 0; nt < 4; ++nt) {
            int m = m0 + wr + mt * 16 + lr;
            int nb = wc + nt * 16 + lq * 4;
            size_t o = (size_t)m * 128 + nb;
            f32x4 qv = *(const f32x4*)&QF[o];
            u16x4 e = e1q[mt][nt];
#pragma unroll
            for (int r = 0; r < 4; ++r) qv[r] += b2f(e[r]) * acc3[mt][nt][r];
            *(f32x4*)&QF[o] = qv;
            q[mt][nt] = qv;
        }
    if (last) return;
    lnmix();   // Hs = hcur-b

    for (int nc = 0; nc < 512; nc += 128) {
        f32x4 acc2[4][4];
#pragma unroll
        for (int i = 0; i < 4; ++i)
#pragma unroll
            for (int j = 0; j < 4; ++j) acc2[i][j] = zero4;
#pragma unroll
        for (int kt2 = 0; kt2 < 128; kt2 += 64) {
            __syncthreads();
#pragma unroll
            for (int i = 0; i < 4; ++i) {
                int id = tid + i * 256;
                int r = id >> 3, c = (id & 7) * 8;
                *(u16x8*)&Bs2[r][c] =
                    *(const u16x8*)&WT4[(size_t)(nc + r) * 128 + kt2 + c];
            }
            __syncthreads();
#pragma unroll
            for (int ks = 0; ks < 2; ++ks) {
                bf16x8 af[4], bfr[4];
#pragma unroll
                for (int t = 0; t < 4; ++t) {
                    af[t]  = *(const bf16x8*)&Hs[wr + t * 16 + lr][kt2 + ks * 32 + lq * 8];
                    bfr[t] = *(const bf16x8*)&Bs2[wc + t * 16 + lr][ks * 32 + lq * 8];
                }
#pragma unroll
                for (int mt = 0; mt < 4; ++mt)
#pragma unroll
                    for (int nt = 0; nt < 4; ++nt)
                        acc2[mt][nt] = __builtin_amdgcn_mfma_f32_16x16x32_bf16(
                            bfr[nt], af[mt], acc2[mt][nt], 0, 0, 0);
            }
        }
#pragma unroll
        for (int mt = 0; mt < 4; ++mt)
#pragma unroll
            for (int nt = 0; nt < 4; ++nt) {
                int m = m0 + wr + mt * 16 + lr;
                int n = nc + wc + nt * 16 + lq * 4;
                f32x4 v = acc2[mt][nt];
                u16x4 t = {f2b(v[0]), f2b(v[1]), f2b(v[2]), f2b(v[3])};
                *(u16x4*)&C4[(size_t)m * 512 + n] = t;
            }
    }
}

// ---------------------------------------------------------------------------
// Windowed attention: one block per (b,w), one wave per head.
// Pitch-136 + Vt XOR swizzle = bank-conflict-free (see R5). Bias is read
// directly from the input tensor (f32 path double-rounds through bf16 to
// stay bit-identical with the old biasbf copy).
// ---------------------------------------------------------------------------
#define VSWZ(d) ((((d) >> 3) & 7) << 3)
__global__ __launch_bounds__(256) void attn_k(
    const u16* __restrict__ proj,
    const void* __restrict__ bias_in,
    const void* __restrict__ mask,
    const int* __restrict__ key_idx,
    u16* __restrict__ o_out,
    const int* __restrict__ dtf)
{
    __shared__ __align__(16) u16 Ks[128][136];
    __shared__ __align__(16) u16 Vt[128][136];
    const int tid = threadIdx.x;
    const int b = blockIdx.x >> 9, w = blockIdx.x & 511;
    int raw = key_idx[w * 128];
    if ((unsigned)raw > (unsigned)(N_ - H_))
        raw = (int)__builtin_bit_cast(float, raw);
    const int ks0 = raw < 0 ? 0 : (raw > N_ - H_ ? N_ - H_ : raw);
    const int lane = tid & 63, h = tid >> 6;
    const int lr = lane & 15, lq = lane >> 4;
    const int hoff = h * 32;
    const int f = dtf[0];

#pragma unroll
    for (int i = 0; i < 8; ++i) {
        int id = tid + i * 256;
        int r = id >> 4, c = (id & 15) * 8;
        size_t gbase = ((size_t)(b * N_ + ks0 + r)) * 512;
        *(u16x8*)&Ks[r][c] = *(const u16x8*)&proj[gbase + 128 + c];
        u16x8 v = *(const u16x8*)&proj[gbase + 256 + c];
#pragma unroll
        for (int j = 0; j < 8; ++j) {
            int d = c + j;
            Vt[d][r ^ VSWZ(d)] = v[j];
        }
    }
    __syncthreads();

    bf16x8 aq[2];
#pragma unroll
    for (int mt = 0; mt < 2; ++mt) {
        int qa = w * 32 + mt * 16 + lr;
        aq[mt] = *(const bf16x8*)&proj[((size_t)(b * N_ + qa)) * 512 + hoff + lq * 8];
    }
    f32x4 zero4 = {0.f, 0.f, 0.f, 0.f};
    f32x4 s[2][8];
#pragma unroll
    for (int nt = 0; nt < 8; ++nt) {
        bf16x8 bk = *(const bf16x8*)&Ks[nt * 16 + lr][hoff + lq * 8];
        s[0][nt] = __builtin_amdgcn_mfma_f32_16x16x32_bf16(aq[0], bk, zero4, 0, 0, 0);
        s[1][nt] = __builtin_amdgcn_mfma_f32_16x16x32_bf16(aq[1], bk, zero4, 0, 0, 0);
    }

    const float scl = 0.17677669529663687f;
    float mb[8];
#pragma unroll
    for (int nt = 0; nt < 8; ++nt)
        mb[nt] = (1.f - ldin(mask, (size_t)b * N_ + ks0 + nt * 16 + lr, f)) * -1e9f;
    size_t bb = (((size_t)b * 512 + w) * 4 + h) * (size_t)(32 * 128);
#pragma unroll
    for (int mt = 0; mt < 2; ++mt)
#pragma unroll
        for (int nt = 0; nt < 8; ++nt)
#pragma unroll
            for (int r = 0; r < 4; ++r) {
                int qq = mt * 16 + lq * 4 + r;
                int kk = nt * 16 + lr;
                size_t bi = bb + (size_t)qq * 128 + kk;
                float bv = f ? b2f(f2b(((const float*)bias_in)[bi]))
                             : b2f(((const u16*)bias_in)[bi]);
                s[mt][nt][r] = s[mt][nt][r] * scl + bv + mb[nt];
            }

#pragma unroll
    for (int mt = 0; mt < 2; ++mt)
#pragma unroll
        for (int r = 0; r < 4; ++r) {
            float mx = -3.4e38f;
#pragma unroll
            for (int nt = 0; nt < 8; ++nt) mx = fmaxf(mx, s[mt][nt][r]);
#pragma unroll
            for (int off = 1; off < 16; off <<= 1) mx = fmaxf(mx, __shfl_xor(mx, off, 64));
            float sm = 0.f;
#pragma unroll
            for (int nt = 0; nt < 8; ++nt) {
                float p = __expf(s[mt][nt][r] - mx);
                s[mt][nt][r] = p; sm += p;
            }
#pragma unroll
            for (int off = 1; off < 16; off <<= 1) sm += __shfl_xor(sm, off, 64);
            float inv = 1.f / sm;
#pragma unroll
            for (int nt = 0; nt < 8; ++nt) s[mt][nt][r] *= inv;
        }

    __syncthreads();
#pragma unroll
    for (int mt = 0; mt < 2; ++mt)
#pragma unroll
        for (int nt = 0; nt < 8; ++nt)
#pragma unroll
            for (int r = 0; r < 4; ++r)
                Ks[hoff + mt * 16 + lq * 4 + r][nt * 16 + lr] = f2b(s[mt][nt][r]);
    __syncthreads();

    f32x4 o[2][2];
    o[0][0] = zero4; o[0][1] = zero4; o[1][0] = zero4; o[1][1] = zero4;
#pragma unroll
    for (int kst = 0; kst < 4; ++kst) {
        bf16x8 ap[2], bv[2];
#pragma unroll
        for (int mt = 0; mt < 2; ++mt)
            ap[mt] = *(const bf16x8*)&Ks[hoff + mt * 16 + lr][kst * 32 + lq * 8];
#pragma unroll
        for (int nt = 0; nt < 2; ++nt) {
            int d = hoff + nt * 16 + lr;
            bv[nt] = *(const bf16x8*)&Vt[d][(kst * 32 + lq * 8) ^ VSWZ(d)];
        }
#pragma unroll
        for (int mt = 0; mt < 2; ++mt)
#pragma unroll
            for (int nt = 0; nt < 2; ++nt)
                o[mt][nt] = __builtin_amdgcn_mfma_f32_16x16x32_bf16(ap[mt], bv[nt], o[mt][nt], 0, 0, 0);
    }

#pragma unroll
    for (int mt = 0; mt < 2; ++mt)
#pragma unroll
        for (int nt = 0; nt < 2; ++nt)
#pragma unroll
            for (int r = 0; r < 4; ++r) {
                int qa = w * 32 + mt * 16 + lq * 4 + r;
                int d = hoff + nt * 16 + lr;
                size_t gi = ((size_t)(b * N_ + qa)) * 512 + 384 + d;
                float g = sigf(b2f(proj[gi]));
                o_out[((size_t)(b * N_ + qa)) * 128 + d] = f2b(g * o[mt][nt][r]);
            }
}

// ---------------------------------------------------------------------------
// Merged prologue: blocks [0,8192) LN(c)->cn; [8192,8192+43*12) weight
// transposes, 64x64 LDS-tiled. TJob.ilv!=0 writes interleaved output rows.
// ---------------------------------------------------------------------------
struct TJob { const void* base; int off; int dst; int K; int N; int ilv; };
struct TJobs { TJob j[43]; };
__global__ __launch_bounds__(256) void prologue_k(
    const void* __restrict__ c_in, u16* __restrict__ cn,
    TJobs jobs, u16* __restrict__ wt, const int* __restrict__ dtf)
{
    __shared__ __align__(16) u16 Ls[64][72];   // 72-pitch keeps u16x8 stores 16B-aligned
    int bx = blockIdx.x;
    int f = dtf[0];
    if (bx < 8192) {
        int row = bx * 4 + (threadIdx.x >> 6);
        int l = threadIdx.x & 63;
        size_t base = (size_t)row * 128;
        float a = ldin(c_in, base + l, f), b = ldin(c_in, base + l + 64, f);
        float s = a + b, ss = a * a + b * b;
#pragma unroll
        for (int off = 1; off < 64; off <<= 1) {
            s  += __shfl_xor(s, off, 64);
            ss += __shfl_xor(ss, off, 64);
        }
        float m = s * (1.f / 128.f);
        float v = ss * (1.f / 128.f) - m * m;
        float inv = rsqrtf(fmaxf(v, 0.f) + 1e-5f);
        cn[base + l]      = f2b((a - m) * inv);
        cn[base + l + 64] = f2b((b - m) * inv);
    } else {
        int t = bx - 8192;
        int jidx = t / 12, tidx = t - jidx * 12;
        TJob jb = jobs.j[jidx];
        int ntk = jb.K >> 6, ntn = jb.N >> 6;       // 64x64 tiles
        if (tidx >= ntk * ntn) return;
        int kt = (tidx % ntk) << 6;
        int nt = (tidx / ntk) << 6;
        int r = threadIdx.x >> 3, cc = (threadIdx.x & 7) * 8;
#pragma unroll
        for (int p = 0; p < 2; ++p) {
            int kl = r + p * 32;
            size_t si = (size_t)jb.off + (size_t)(kt + kl) * jb.N + nt + cc;
            u16x8 v;
            if (f) {
                const float* s = (const float*)jb.base;
                f32x4 p0 = *(const f32x4*)&s[si];
                f32x4 p1 = *(const f32x4*)&s[si + 4];
                v[0] = f2b(p0[0]); v[1] = f2b(p0[1]); v[2] = f2b(p0[2]); v[3] = f2b(p0[3]);
                v[4] = f2b(p1[0]); v[5] = f2b(p1[1]); v[6] = f2b(p1[2]); v[7] = f2b(p1[3]);
            } else {
                v = *(const u16x8*)&((const u16*)jb.base)[si];
            }
            *(u16x8*)&Ls[kl][cc] = v;
        }
        __syncthreads();
#pragma unroll
        for (int p = 0; p < 2; ++p) {
            int nl = r + p * 32;
            u16x8 w;
#pragma unroll
            for (int j = 0; j < 8; ++j) w[j] = Ls[cc + j][nl];
            int fcol = nt + nl;
            size_t orow = jb.ilv
                ? (size_t)(((fcol >> 6) << 7) + ((fcol & 63) << 1) + (jb.ilv - 1))
                : (size_t)fcol;
            *(u16x8*)&wt[(size_t)jb.dst + orow * jb.K + kt + cc] = w;
        }
    }
}

// ---------------------------------------------------------------------------
// initq + first LN-mix: qf = q_in + aw[token]; hcur = LN(qf)*cs0 + cb0.
// ---------------------------------------------------------------------------
__global__ __launch_bounds__(256) void initq_ln_k(
    const void* __restrict__ qin, const float* __restrict__ aw,
    float* __restrict__ qf,
    const u16* __restrict__ cs0, const u16* __restrict__ cb0, int sgcbld,
    u16* __restrict__ hcur, const int* __restrict__ dtf)
{
    int an = blockIdx.x * 4 + (threadIdx.x >> 6);
    int l = threadIdx.x & 63;
    int f = dtf[0];
    int b = an >> 14, n = an & 16383, t = n >> 3;
    size_t base = (size_t)an * 128;
    size_t ab = ((size_t)b * T_ + t) * 128;
    float a0 = ldin(qin, base + l, f)      + aw[ab + l];
    float a1 = ldin(qin, base + l + 64, f) + aw[ab + l + 64];
    qf[base + l] = a0; qf[base + l + 64] = a1;
    float s = a0 + a1, ss = a0 * a0 + a1 * a1;
#pragma unroll
    for (int off = 1; off < 64; off <<= 1) {
        s  += __shfl_xor(s, off, 64);
        ss += __shfl_xor(ss, off, 64);
    }
    float m = s * (1.f / 128.f);
    float v = ss * (1.f / 128.f) - m * m;
    float inv = rsqrtf(fmaxf(v, 0.f) + 1e-5f);
    size_t sb = (size_t)an * sgcbld;
    hcur[base + l]      = f2b((a0 - m) * inv * b2f(cs0[sb + l])      + b2f(cb0[sb + l]));
    hcur[base + l + 64] = f2b((a1 - m) * inv * b2f(cs0[sb + l + 64]) + b2f(cb0[sb + l + 64]));
}

// ---------------------------------------------------------------------------
// Merged finals: blocks [0,8192) r_update; [8192,9216) res_type (wave/token).
// ---------------------------------------------------------------------------
__global__ __launch_bounds__(256) void final_k(const float* __restrict__ q,
    const void* __restrict__ ln_g, const void* __restrict__ ln_b,
    const void* __restrict__ Wpos,
    const void* __restrict__ mask, const void* __restrict__ Wres,
    const void* __restrict__ bres,
    float* __restrict__ out1, float* __restrict__ out2,
    const int* __restrict__ dtf)
{
    int f = dtf[0];
    int bx = blockIdx.x;
    if (bx < 8192) {
        int row = bx * 4 + (threadIdx.x >> 6);
        int l = threadIdx.x & 63;
        size_t base = (size_t)row * 128;
        float a = q[base + l], b = q[base + l + 64];
        float s = a + b, ss = a * a + b * b;
#pragma unroll
        for (int off = 1; off < 64; off <<= 1) {
            s  += __shfl_xor(s, off, 64);
            ss += __shfl_xor(ss, off, 64);
        }
        float m = s * (1.f / 128.f);
        float v = ss * (1.f / 128.f) - m * m;
        float inv = rsqrtf(fmaxf(v, 0.f) + 1e-5f);
        float y0 = (a - m) * inv * ldin(ln_g, l, f)      + ldin(ln_b, l, f);
        float y1 = (b - m) * inv * ldin(ln_g, l + 64, f) + ldin(ln_b, l + 64, f);
        float p0 = y0 * ldin(Wpos, l * 3 + 0, f) + y1 * ldin(Wpos, (l + 64) * 3 + 0, f);
        float p1 = y0 * ldin(Wpos, l * 3 + 1, f) + y1 * ldin(Wpos, (l + 64) * 3 + 1, f);
        float p2 = y0 * ldin(Wpos, l * 3 + 2, f) + y1 * ldin(Wpos, (l + 64) * 3 + 2, f);
#pragma unroll
        for (int off = 1; off < 64; off <<= 1) {
            p0 += __shfl_xor(p0, off, 64);
            p1 += __shfl_xor(p1, off, 64);
            p2 += __shfl_xor(p2, off, 64);
        }
        if (l == 0) {
            out1[(size_t)row * 3 + 0] = p0;
            out1[(size_t)row * 3 + 1] = p1;
            out1[(size_t)row * 3 + 2] = p2;
        }
    } else {
        __shared__ float sfeat[4][128];
        int wid = threadIdx.x >> 6, l = threadIdx.x & 63;
        int tok = (bx - 8192) * 4 + wid;
        int b = tok >> 11, t = tok & 2047;
        float a0 = 0.f, a1 = 0.f;
#pragma unroll
        for (int i = 0; i < 8; ++i) {
            size_t an = (size_t)b * N_ + t * 8 + i;
            float mk = ldin(mask, an, f);
            a0 += q[an * 128 + l] * mk;
            a1 += q[an * 128 + l + 64] * mk;
        }
        sfeat[wid][l] = a0; sfeat[wid][l + 64] = a1;
        __builtin_amdgcn_s_waitcnt(0);  // wave-local LDS visibility
        if (l < NTOK_) {
            float r = ldin(bres, l, f);
            for (int d = 0; d < 128; ++d) r += sfeat[wid][d] * ldin(Wres, d * NTOK_ + l, f);
            out2[(size_t)tok * NTOK_ + l] = r;
        }
    }
}

// ---------------------------------------------------------------------------
// Workspace layout (bytes), ws = 1 GiB:
//   wt      : 0           weight arena (flag int at 2,088,960)
//   qf      : 2,097,152    f32 BN x 128
//   cn      : 18,874,368   bf16
//   cnprojS : 60,817,408   bf16 BN x 256 [cb0 | cs0]
//   hcur    : 211,812,352  bf16 (layer-0 attn input only)
//   proj    : 220,200,960  bf16 BN x 512
//   obuf    : 253,755,392  bf16
//   aw      : 262,144,000  f32 (prologue only)
// ---------------------------------------------------------------------------
extern "C" void kernel_launch(void* const* d_in, const int* in_sizes, int n_in,
                              void* d_out, int out_size, void* d_ws, size_t ws_size,
                              hipStream_t stream)
{
    (void)out_size;
    float* out = (float*)d_out;
    const size_t WS_NEED = 295698432;

    static const int EXP_SZ[27] = {
        1572864, 4194304, 4194304, 16777216, 67108864, 32768, 65536,
        49152, 49152, 49152, 49152, 49152, 49152,
        49152, 49152, 49152, 49152, 49152, 49152,
        98304, 98304, 98304, 128, 128, 384, 4224, 33 };
    int bad = -1;
    int ncheck = n_in < 27 ? n_in : 27;
    for (int i = 0; i < ncheck; ++i)
        if (in_sizes[i] != EXP_SZ[i]) { bad = i; break; }
    if (bad >= 0) { sentinel_k<<<1, 64, 0, stream>>>(out, 256.0f * (bad + 1)); return; }
    if (n_in < 27) { sentinel_k<<<1, 64, 0, stream>>>(out, 8192.0f); return; }
    if (ws_size < WS_NEED) { sentinel_k<<<1, 64, 0, stream>>>(out, 12288.0f); return; }

    const void* a_in    = d_in[0];
    const void* q_in    = d_in[1];
    const void* c_in    = d_in[2];
    const void* bias_in = d_in[3];
    const void* mask_in = d_in[5];
    const int*  kidx    = (const int*)d_in[6];
    const void* a2q  = d_in[7];
    const void* Wq   = d_in[8];
    const void* Wk   = d_in[9];
    const void* Wv   = d_in[10];
    const void* Wg   = d_in[11];
    const void* Wo   = d_in[12];
    const void* Wcs  = d_in[13];
    const void* Wcb  = d_in[14];
    const void* Wog  = d_in[15];
    const void* Wcs2 = d_in[16];
    const void* Wcb2 = d_in[17];
    const void* Wog2 = d_in[18];
    const void* W1   = d_in[19];
    const void* W2   = d_in[20];
    const void* W3   = d_in[21];
    const void* ln_g = d_in[22];
    const void* ln_b = d_in[23];
    const void* Wpos = d_in[24];
    const void* Wres = d_in[25];
    const void* bres = d_in[26];

    char* ws = (char*)d_ws;
    u16*   wt      = (u16*)ws;
    int*   flag    = (int*)(ws + 2088960);
    float* qf      = (float*)(ws + 2097152);
    u16*   cn      = (u16*)(ws + 18874368);
    u16*   cnprojS = (u16*)(ws + 60817408);
    u16*   hcur    = (u16*)(ws + 211812352);
    u16*   proj    = (u16*)(ws + 220200960);
    u16*   obuf    = (u16*)(ws + 253755392);
    float* aw      = (float*)(ws + 262144000);

    detect_k<<<1, 64, 0, stream>>>((const u16*)a_in, flag);

    // weight arena (elements):
    //   0..196608       Wq|Wk|Wv|Wg per layer (l*65536)
    //   196608 cb0 | 212992 cs0
    //   229376 og[l] | 278528 cs2[l] | 327680 cb2[l] | 376832 og2[l]
    //   425984 cs[1],cs[2] | 458752 cb[1],cb[2]
    //   491520 w12 INTERLEAVED arena | 688128 W3 | 786432 a2q | 835584 Wo
    TJobs jobs; int nj = 0;
    for (int l = 0; l < 3; ++l) {
        jobs.j[nj++] = {Wq,   l * 16384, l * 65536 + 0,     128, 128, 0};
        jobs.j[nj++] = {Wk,   l * 16384, l * 65536 + 16384, 128, 128, 0};
        jobs.j[nj++] = {Wv,   l * 16384, l * 65536 + 32768, 128, 128, 0};
        jobs.j[nj++] = {Wg,   l * 16384, l * 65536 + 49152, 128, 128, 0};
        jobs.j[nj++] = {Wog,  l * 16384, 229376 + l * 16384, 128, 128, 0};
        jobs.j[nj++] = {Wcs2, l * 16384, 278528 + l * 16384, 128, 128, 0};
        jobs.j[nj++] = {Wcb2, l * 16384, 327680 + l * 16384, 128, 128, 0};
        jobs.j[nj++] = {Wog2, l * 16384, 376832 + l * 16384, 128, 128, 0};
        jobs.j[nj++] = {W1,   l * 32768, 491520 + l * 65536, 128, 256, 1};
        jobs.j[nj++] = {W2,   l * 32768, 491520 + l * 65536, 128, 256, 2};
        jobs.j[nj++] = {W3,   l * 32768, 688128 + l * 32768, 256, 128, 0};
        jobs.j[nj++] = {Wo,   l * 16384, 835584 + l * 16384, 128, 128, 0};
    }
    jobs.j[nj++] = {Wcb, 0,     196608, 128, 128, 0};
    jobs.j[nj++] = {Wcs, 0,     212992, 128, 128, 0};
    jobs.j[nj++] = {Wcs, 16384, 425984, 128, 128, 0};
    jobs.j[nj++] = {Wcs, 32768, 442368, 128, 128, 0};
    jobs.j[nj++] = {Wcb, 16384, 458752, 128, 128, 0};
    jobs.j[nj++] = {Wcb, 32768, 475136, 128, 128, 0};
    jobs.j[nj++] = {a2q, 0,     786432, 384, 128, 0};

    prologue_k<<<8192 + 43 * 12, 256, 0, stream>>>(c_in, cn, jobs, wt, flag);
    // aw = a @ a2q (M=4096, K=384, asrc=1)
    gemm_k<<<dim3(32, 1), 256, 0, stream>>>(
        (const u16*)a_in, S_, 1, wt + 786432, S_, nullptr, D_, aw, M_F32, flag);
    // cnprojS = [cb0 | sig(cs0)]
    gemm_k<<<dim3(256, 2), 256, 0, stream>>>(
        cn, D_, 0, wt + 196608, D_, cnprojS, 256, nullptr, M_CBSG, nullptr);
    // qf init + layer-0 attention-half hcur
    initq_ln_k<<<8192, 256, 0, stream>>>(q_in, aw, qf,
        cnprojS + 128, cnprojS + 0, 256, hcur, flag);

    // layer-0 attention projections
    gemm_k<<<dim3(256, 4), 256, 0, stream>>>(
        hcur, D_, 0, wt + 0, D_, proj, 512, nullptr, M_STORE, nullptr);

    for (int l = 0; l < 3; ++l) {
        const u16* wt_proj_n = wt + (l + 1) * 65536;
        const u16* wt_w12  = wt + 491520 + l * 65536;
        const u16* wt_w3   = wt + 688128 + l * 32768;
        const u16* wt_wo   = wt + 835584 + l * 16384;
        const u16* wt_og   = wt + 229376 + l * 16384;
        const u16* wt_cs2  = wt + 278528 + l * 16384;
        const u16* wt_cb2  = wt + 327680 + l * 16384;
        const u16* wt_og2  = wt + 376832 + l * 16384;
        const u16* wt_cs_n = wt + 425984 + l * 16384;   // Wcs[l+1] (l<2)
        const u16* wt_cb_n = wt + 458752 + l * 16384;   // Wcb[l+1] (l<2)

        attn_k<<<1024, 256, 0, stream>>>(proj, bias_in, mask_in, kidx, obuf, flag);
        // one merged kernel per layer: Wo-residual + LN + FFN (u12 in LDS) +
        // W3-residual + LN + next-layer proj
        fres_k<<<256, 256, 0, stream>>>(
            obuf, cn, wt_wo, wt_og, wt_cs2, wt_cb2,
            wt_w12, wt_w3, wt_og2,
            l < 2 ? wt_cs_n : nullptr, l < 2 ? wt_cb_n : nullptr,
            qf,
            l < 2 ? wt_proj_n : nullptr, proj, l == 2 ? 1 : 0);
    }

    final_k<<<9216, 256, 0, stream>>>(qf, ln_g, ln_b, Wpos, mask_in, Wres, bres,
                                      out, out + (size_t)BN_ * 3, flag);
}

// Round 10
// 801.598 us; speedup vs baseline: 1.1191x; 1.1162x over previous
//
#include <hip/hip_runtime.h>

typedef unsigned short u16;
typedef u16 u16x2 __attribute__((ext_vector_type(2)));
typedef u16 u16x4 __attribute__((ext_vector_type(4)));
typedef u16 u16x8 __attribute__((ext_vector_type(8)));
typedef __bf16 bf16x8 __attribute__((ext_vector_type(8)));
typedef float f32x4 __attribute__((ext_vector_type(4)));

#define B_  2
#define N_  16384
#define T_  2048
#define D_  128
#define S_  384
#define NW_ 512
#define WQ_ 32
#define H_  128
#define L_  3
#define NH_ 4
#define NTOK_ 33
#define BN_ (B_*N_)

__device__ __forceinline__ float b2f(u16 u) {
    return __builtin_bit_cast(float, ((unsigned)u) << 16);
}
__device__ __forceinline__ u16 f2b(float f) {
    unsigned x = __builtin_bit_cast(unsigned, f);
    unsigned r = x + 0x7fffu + ((x >> 16) & 1u);   // RNE
    return (u16)(r >> 16);
}
__device__ __forceinline__ float sigf(float x) { return 1.f / (1.f + __expf(-x)); }
__device__ __forceinline__ float ldin(const void* p, size_t i, int f) {
    return f ? ((const float*)p)[i] : b2f(((const u16*)p)[i]);
}

enum { M_STORE = 0, M_CBSG = 1, M_F32 = 2 };

__global__ void sentinel_k(float* out, float v) { if (threadIdx.x == 0) out[0] = v; }

// Detect input storage dtype from tensor `a`. flag=1 -> f32.
__global__ __launch_bounds__(64) void detect_k(const u16* __restrict__ a, int* flag)
{
    int t = threadIdx.x;
    u16 u = a[2 * t];
    int e = (u >> 7) & 0xFF;
    bool inval = (u != 0) && (e < 96 || e > 143);
    unsigned long long m = __ballot(inval);
    if (t == 0) flag[0] = (__popcll(m) >= 6) ? 1 : 0;
}

// ---------------------------------------------------------------------------
// Plain GEMM: C[m,n] = sum_k A[m,k]*W[k,n], W pre-transposed WT[n,k].
// Tile 128x128, BK=64, 4 waves of 64x64. Swapped-operand MFMA (mfma(b,a)):
// lane's 4 acc regs = 4 consecutive n at fixed m -> vectorized epilogue.
// ---------------------------------------------------------------------------
__global__ __launch_bounds__(256) void gemm_k(
    const u16* __restrict__ A, int lda, int asrc,
    const u16* __restrict__ WT, int K,
    u16* __restrict__ C, int ldc,
    float* __restrict__ QF, int mode, const int* __restrict__ dtf)
{
    __shared__ __align__(16) char smem[36864];
    u16 (*As)[72] = (u16(*)[72])smem;
    u16 (*Bs)[72] = (u16(*)[72])(smem + 18432);

    const int tid = threadIdx.x;
    const int m0 = blockIdx.x * 128, n0 = blockIdx.y * 128;
    const int lane = tid & 63, wid = tid >> 6;
    const int wr = (wid >> 1) * 64, wc = (wid & 1) * 64;
    const int lr = lane & 15, lq = lane >> 4;
    const int af32 = (asrc == 1 && dtf) ? dtf[0] : 0;

    f32x4 zero4 = {0.f, 0.f, 0.f, 0.f};
    f32x4 acc[4][4];
#pragma unroll
    for (int i = 0; i < 4; ++i)
#pragma unroll
        for (int j = 0; j < 4; ++j) acc[i][j] = zero4;

    for (int kt = 0; kt < K; kt += 64) {
#pragma unroll
        for (int i = 0; i < 4; ++i) {
            int id = tid + i * 256;
            int r = id >> 3, c = (id & 7) * 8;
            if (af32) {
                const float* Af = (const float*)A;
                size_t ai = (size_t)(m0 + r) * lda + kt + c;
                f32x4 p0 = *(const f32x4*)&Af[ai];
                f32x4 p1 = *(const f32x4*)&Af[ai + 4];
                u16x8 t;
                t[0] = f2b(p0[0]); t[1] = f2b(p0[1]); t[2] = f2b(p0[2]); t[3] = f2b(p0[3]);
                t[4] = f2b(p1[0]); t[5] = f2b(p1[1]); t[6] = f2b(p1[2]); t[7] = f2b(p1[3]);
                *(u16x8*)&As[r][c] = t;
            } else {
                *(u16x8*)&As[r][c] = *(const u16x8*)&A[(size_t)(m0 + r) * lda + kt + c];
            }
            *(u16x8*)&Bs[r][c] = *(const u16x8*)&WT[(size_t)(n0 + r) * K + kt + c];
        }
        __syncthreads();
#pragma unroll
        for (int ks = 0; ks < 2; ++ks) {
            bf16x8 af[4], bfr[4];
#pragma unroll
            for (int t = 0; t < 4; ++t) {
                af[t]  = *(const bf16x8*)&As[wr + t * 16 + lr][ks * 32 + lq * 8];
                bfr[t] = *(const bf16x8*)&Bs[wc + t * 16 + lr][ks * 32 + lq * 8];
            }
#pragma unroll
            for (int mt = 0; mt < 4; ++mt)
#pragma unroll
                for (int nt = 0; nt < 4; ++nt)
                    acc[mt][nt] = __builtin_amdgcn_mfma_f32_16x16x32_bf16(
                        bfr[nt], af[mt], acc[mt][nt], 0, 0, 0);
        }
        __syncthreads();
    }

    const bool sig_half = (n0 >= 128);   // for M_CBSG (cb0 | cs0 pair)
#pragma unroll
    for (int mt = 0; mt < 4; ++mt)
#pragma unroll
        for (int nt = 0; nt < 4; ++nt) {
            int lm = wr + mt * 16 + lr;
            int lnb = wc + nt * 16 + lq * 4;
            int m = m0 + lm;
            size_t o = (size_t)m * ldc + n0 + lnb;
            f32x4 v = acc[mt][nt];
            if (mode == M_STORE) {
                u16x4 t = {f2b(v[0]), f2b(v[1]), f2b(v[2]), f2b(v[3])};
                *(u16x4*)&C[o] = t;
            } else if (mode == M_CBSG) {
                u16x4 t;
#pragma unroll
                for (int r = 0; r < 4; ++r) t[r] = f2b(sig_half ? sigf(v[r]) : v[r]);
                *(u16x4*)&C[o] = t;
            } else {  // M_F32
                *(f32x4*)&QF[o] = v;
            }
        }
}

// ---------------------------------------------------------------------------
// Merged per-layer residual kernel (grid 256, 1 block per 128 rows).
// Phase-a writes QF, phase-b re-reads it (R7 semantics; q dead in FFN).
// cn persists in a dedicated LDS buffer (no phase-b re-stage). u12 lives
// only in LDS (interleaved W1/W2 arena + in-register silu).
// ---------------------------------------------------------------------------
__global__ __launch_bounds__(256) void fres_k(
    const u16* __restrict__ A,          // obuf (128-wide bf16)
    const u16* __restrict__ cnb,
    const u16* __restrict__ WT1,        // Wo^T [128][128]
    const u16* __restrict__ WEa, const u16* __restrict__ WSa, const u16* __restrict__ WBa,
    const u16* __restrict__ W12,        // interleaved [512][128]
    const u16* __restrict__ W3T,        // [128][256]
    const u16* __restrict__ WEb, const u16* __restrict__ WSb, const u16* __restrict__ WBb,
    float* __restrict__ QF,
    const u16* __restrict__ WT4, u16* __restrict__ C4,   // Wqkv(l+1)^T, proj
    int last)
{
    __shared__ __align__(16) char smem[108544];
    u16 (*Cs)[136] = (u16(*)[136])smem;                   // cn tile (persistent)
    u16 (*Hs)[136] = (u16(*)[136])(smem + 34816);         // LN output
    u16 (*Bw)[136] = (u16(*)[136])(smem + 69632);         // pre-gemm weight tile
    u16 (*As)[72]  = (u16(*)[72])(smem + 69632);          // stage-1 A
    u16 (*Bs)[72]  = (u16(*)[72])(smem + 69632 + 18432);  // stage-1 B
    u16 (*Bs2)[72] = (u16(*)[72])(smem + 69632);          // chunk B tiles
    u16 (*Ut)[72]  = (u16(*)[72])(smem + 69632 + 18432);  // fused silu tile
    float* LNp = (float*)(smem + 106496);                 // [4][64][2]

    const int tid = threadIdx.x;
    const int m0 = blockIdx.x * 128;
    const int lane = tid & 63, wid = tid >> 6;
    const int wr = (wid >> 1) * 64, wc = (wid & 1) * 64;
    const int lr = lane & 15, lq = lane >> 4;
    f32x4 zero4 = {0.f, 0.f, 0.f, 0.f};

    u16x4 e1q[4][4], sgq[4][4], cbq[4][4];
    f32x4 q[4][4];

    auto pregemm = [&](const u16* Wp, int dosig, u16x4 (*out)[4]) {
#pragma unroll
        for (int i = 0; i < 8; ++i) {
            int id = tid + i * 256;
            int r = id >> 4, c = (id & 15) * 8;
            *(u16x8*)&Bw[r][c] = *(const u16x8*)&Wp[(size_t)r * 128 + c];
        }
        __syncthreads();
        f32x4 pacc[4][4];
#pragma unroll
        for (int i = 0; i < 4; ++i)
#pragma unroll
            for (int j = 0; j < 4; ++j) pacc[i][j] = zero4;
#pragma unroll
        for (int kk = 0; kk < 4; ++kk) {
            bf16x8 af[4], bfr[4];
#pragma unroll
            for (int t = 0; t < 4; ++t) {
                af[t]  = *(const bf16x8*)&Cs[wr + t * 16 + lr][kk * 32 + lq * 8];
                bfr[t] = *(const bf16x8*)&Bw[wc + t * 16 + lr][kk * 32 + lq * 8];
            }
#pragma unroll
            for (int mt = 0; mt < 4; ++mt)
#pragma unroll
                for (int nt = 0; nt < 4; ++nt)
                    pacc[mt][nt] = __builtin_amdgcn_mfma_f32_16x16x32_bf16(
                        bfr[nt], af[mt], pacc[mt][nt], 0, 0, 0);
        }
        __syncthreads();
#pragma unroll
        for (int mt = 0; mt < 4; ++mt)
#pragma unroll
            for (int nt = 0; nt < 4; ++nt) {
                u16x4 t;
#pragma unroll
                for (int r = 0; r < 4; ++r) {
                    float v = pacc[mt][nt][r];
                    t[r] = f2b(dosig ? sigf(v) : v);
                }
                out[mt][nt] = t;
            }
    };

    auto lnmix = [&]() {
        float s0[4], sq0[4];
#pragma unroll
        for (int mt = 0; mt < 4; ++mt) {
            float s = 0.f, sq = 0.f;
#pragma unroll
            for (int nt = 0; nt < 4; ++nt)
#pragma unroll
                for (int r = 0; r < 4; ++r) {
                    float v = q[mt][nt][r];
                    s += v; sq += v * v;
                }
            s  += __shfl_xor(s, 16, 64);  sq += __shfl_xor(sq, 16, 64);
            s  += __shfl_xor(s, 32, 64);  sq += __shfl_xor(sq, 32, 64);
            s0[mt] = s; sq0[mt] = sq;
        }
        if (lq == 0) {
#pragma unroll
            for (int mt = 0; mt < 4; ++mt) {
                int row = mt * 16 + lr;
                LNp[wid * 128 + row * 2 + 0] = s0[mt];
                LNp[wid * 128 + row * 2 + 1] = sq0[mt];
            }
        }
        __syncthreads();
#pragma unroll
        for (int mt = 0; mt < 4; ++mt) {
            int row = mt * 16 + lr;
            int w0 = wid & 2;
            float S  = LNp[w0 * 128 + row * 2 + 0] + LNp[(w0 + 1) * 128 + row * 2 + 0];
            float SQ = LNp[w0 * 128 + row * 2 + 1] + LNp[(w0 + 1) * 128 + row * 2 + 1];
            float mu = S * (1.f / 128.f);
            float var = SQ * (1.f / 128.f) - mu * mu;
            float inv = rsqrtf(fmaxf(var, 0.f) + 1e-5f);
            int lm = wr + mt * 16 + lr;
#pragma unroll
            for (int nt = 0; nt < 4; ++nt) {
                u16x4 sg = sgq[mt][nt], cb = cbq[mt][nt];
                u16x4 hv;
#pragma unroll
                for (int r = 0; r < 4; ++r)
                    hv[r] = f2b((q[mt][nt][r] - mu) * inv * b2f(sg[r]) + b2f(cb[r]));
                *(u16x4*)&Hs[lm][wc + nt * 16 + lq * 4] = hv;
            }
        }
    };

    // ---- phase a ----
#pragma unroll
    for (int i = 0; i < 8; ++i) {            // stage cn once (persistent)
        int id = tid + i * 256;
        int r = id >> 4, c = (id & 15) * 8;
        *(u16x8*)&Cs[r][c] = *(const u16x8*)&cnb[(size_t)(m0 + r) * 128 + c];
    }
    pregemm(WEa, 1, e1q);
    pregemm(WSa, 1, sgq);
    pregemm(WBa, 0, cbq);

    f32x4 acc[4][4];
#pragma unroll
    for (int i = 0; i < 4; ++i)
#pragma unroll
        for (int j = 0; j < 4; ++j) acc[i][j] = zero4;
    for (int kt = 0; kt < 128; kt += 64) {
#pragma unroll
        for (int i = 0; i < 4; ++i) {
            int id = tid + i * 256;
            int r = id >> 3, c = (id & 7) * 8;
            *(u16x8*)&As[r][c] = *(const u16x8*)&A[(size_t)(m0 + r) * 128 + kt + c];
            *(u16x8*)&Bs[r][c] = *(const u16x8*)&WT1[(size_t)r * 128 + kt + c];
        }
        __syncthreads();
#pragma unroll
        for (int ks = 0; ks < 2; ++ks) {
            bf16x8 af[4], bfr[4];
#pragma unroll
            for (int t = 0; t < 4; ++t) {
                af[t]  = *(const bf16x8*)&As[wr + t * 16 + lr][ks * 32 + lq * 8];
                bfr[t] = *(const bf16x8*)&Bs[wc + t * 16 + lr][ks * 32 + lq * 8];
            }
#pragma unroll
            for (int mt = 0; mt < 4; ++mt)
#pragma unroll
                for (int nt = 0; nt < 4; ++nt)
                    acc[mt][nt] = __builtin_amdgcn_mfma_f32_16x16x32_bf16(
                        bfr[nt], af[mt], acc[mt][nt], 0, 0, 0);
        }
        __syncthreads();
    }
    // residual a: q = QF + E1a*acc; WRITE QF (q dead in FFN)
#pragma unroll
    for (int mt = 0; mt < 4; ++mt)
#pragma unroll
        for (int nt = 0; nt < 4; ++nt) {
            int m = m0 + wr + mt * 16 + lr;
            int nb = wc + nt * 16 + lq * 4;
            size_t o = (size_t)m * 128 + nb;
            f32x4 qv = *(const f32x4*)&QF[o];
            u16x4 e = e1q[mt][nt];
#pragma unroll
            for (int r = 0; r < 4; ++r) qv[r] += b2f(e[r]) * acc[mt][nt][r];
            *(f32x4*)&QF[o] = qv;
            q[mt][nt] = qv;
        }
    lnmix();   // Hs = hcur-a

    // ---- FFN chunks: u12 in LDS only ----
    f32x4 acc3[4][4];
#pragma unroll
    for (int i = 0; i < 4; ++i)
#pragma unroll
        for (int j = 0; j < 4; ++j) acc3[i][j] = zero4;

    for (int ch = 0; ch < 4; ++ch) {
        f32x4 acc2[4][4];
#pragma unroll
        for (int i = 0; i < 4; ++i)
#pragma unroll
            for (int j = 0; j < 4; ++j) acc2[i][j] = zero4;
#pragma unroll
        for (int kt2 = 0; kt2 < 128; kt2 += 64) {
            __syncthreads();
#pragma unroll
            for (int i = 0; i < 4; ++i) {
                int id = tid + i * 256;
                int r = id >> 3, c = (id & 7) * 8;
                *(u16x8*)&Bs2[r][c] =
                    *(const u16x8*)&W12[(size_t)(ch * 128 + r) * 128 + kt2 + c];
            }
            __syncthreads();
#pragma unroll
            for (int ks = 0; ks < 2; ++ks) {
                bf16x8 af[4], bfr[4];
#pragma unroll
                for (int t = 0; t < 4; ++t) {
                    af[t]  = *(const bf16x8*)&Hs[wr + t * 16 + lr][kt2 + ks * 32 + lq * 8];
                    bfr[t] = *(const bf16x8*)&Bs2[wc + t * 16 + lr][ks * 32 + lq * 8];
                }
#pragma unroll
                for (int mt = 0; mt < 4; ++mt)
#pragma unroll
                    for (int nt = 0; nt < 4; ++nt)
                        acc2[mt][nt] = __builtin_amdgcn_mfma_f32_16x16x32_bf16(
                            bfr[nt], af[mt], acc2[mt][nt], 0, 0, 0);
            }
        }
        // silu pairs (even n = W1, odd n = W2 of same fused col); round to
        // bf16 first so the math matches the old u12 HBM path bit-for-bit.
#pragma unroll
        for (int mt = 0; mt < 4; ++mt)
#pragma unroll
            for (int nt = 0; nt < 4; ++nt) {
                f32x4 v = acc2[mt][nt];
                float a0 = b2f(f2b(v[0])), a1 = b2f(f2b(v[1]));
                float a2 = b2f(f2b(v[2])), a3 = b2f(f2b(v[3]));
                u16x2 t;
                t[0] = f2b(a0 * sigf(a0) * a1);
                t[1] = f2b(a2 * sigf(a2) * a3);
                int lm = wr + mt * 16 + lr;
                int fc = (wc >> 1) + nt * 8 + lq * 2;
                *(u16x2*)&Ut[lm][fc] = t;
            }
        __syncthreads();
#pragma unroll
        for (int i = 0; i < 4; ++i) {
            int id = tid + i * 256;
            int r = id >> 3, c = (id & 7) * 8;
            *(u16x8*)&Bs2[r][c] = *(const u16x8*)&W3T[(size_t)r * 256 + ch * 64 + c];
        }
        __syncthreads();
#pragma unroll
        for (int ks = 0; ks < 2; ++ks) {
            bf16x8 af[4], bfr[4];
#pragma unroll
            for (int t = 0; t < 4; ++t) {
                af[t]  = *(const bf16x8*)&Ut[wr + t * 16 + lr][ks * 32 + lq * 8];
                bfr[t] = *(const bf16x8*)&Bs2[wc + t * 16 + lr][ks * 32 + lq * 8];
            }
#pragma unroll
            for (int mt = 0; mt < 4; ++mt)
#pragma unroll
                for (int nt = 0; nt < 4; ++nt)
                    acc3[mt][nt] = __builtin_amdgcn_mfma_f32_16x16x32_bf16(
                        bfr[nt], af[mt], acc3[mt][nt], 0, 0, 0);
        }
    }

    // ---- phase b ----
    __syncthreads();
    pregemm(WEb, 1, e1q);
    if (!last) {
        pregemm(WSb, 1, sgq);
        pregemm(WBb, 0, cbq);
    }
    // residual b: re-read QF, add E1b*acc3, write QF
#pragma unroll
    for (int mt = 0; mt < 4; ++mt)
#pragma unroll
        for (int nt = 0; nt < 4; ++nt) {
            int m = m0 + wr + mt * 16 + lr;
            int nb = wc + nt * 16 + lq * 4;
            size_t o = (size_t)m * 128 + nb;
            f32x4 qv = *(const f32x4*)&QF[o];
            u16x4 e = e1q[mt][nt];
#pragma unroll
            for (int r = 0; r < 4; ++r) qv[r] += b2f(e[r]) * acc3[mt][nt][r];
            *(f32x4*)&QF[o] = qv;
            q[mt][nt] = qv;
        }
    if (last) return;
    lnmix();   // Hs = hcur-b

    for (int nc = 0; nc < 512; nc += 128) {
        f32x4 acc2[4][4];
#pragma unroll
        for (int i = 0; i < 4; ++i)
#pragma unroll
            for (int j = 0; j < 4; ++j) acc2[i][j] = zero4;
#pragma unroll
        for (int kt2 = 0; kt2 < 128; kt2 += 64) {
            __syncthreads();
#pragma unroll
            for (int i = 0; i < 4; ++i) {
                int id = tid + i * 256;
                int r = id >> 3, c = (id & 7) * 8;
                *(u16x8*)&Bs2[r][c] =
                    *(const u16x8*)&WT4[(size_t)(nc + r) * 128 + kt2 + c];
            }
            __syncthreads();
#pragma unroll
            for (int ks = 0; ks < 2; ++ks) {
                bf16x8 af[4], bfr[4];
#pragma unroll
                for (int t = 0; t < 4; ++t) {
                    af[t]  = *(const bf16x8*)&Hs[wr + t * 16 + lr][kt2 + ks * 32 + lq * 8];
                    bfr[t] = *(const bf16x8*)&Bs2[wc + t * 16 + lr][ks * 32 + lq * 8];
                }
#pragma unroll
                for (int mt = 0; mt < 4; ++mt)
#pragma unroll
                    for (int nt = 0; nt < 4; ++nt)
                        acc2[mt][nt] = __builtin_amdgcn_mfma_f32_16x16x32_bf16(
                            bfr[nt], af[mt], acc2[mt][nt], 0, 0, 0);
            }
        }
#pragma unroll
        for (int mt = 0; mt < 4; ++mt)
#pragma unroll
            for (int nt = 0; nt < 4; ++nt) {
                int m = m0 + wr + mt * 16 + lr;
                int n = nc + wc + nt * 16 + lq * 4;
                f32x4 v = acc2[mt][nt];
                u16x4 t = {f2b(v[0]), f2b(v[1]), f2b(v[2]), f2b(v[3])};
                *(u16x4*)&C4[(size_t)m * 512 + n] = t;
            }
    }
}

// ---------------------------------------------------------------------------
// Windowed attention: one block per (b,w), one wave per head.
// Pitch-136 + Vt XOR swizzle = bank-conflict-free (see R5). R10: bias comes
// from the prologue-converted bf16 biasbf again -- R8's direct f32 read put
// 67 MB of latency-bound scattered loads inside this 2-block/CU kernel
// (net-zero traffic change, big latency cost).
// ---------------------------------------------------------------------------
#define VSWZ(d) ((((d) >> 3) & 7) << 3)
__global__ __launch_bounds__(256) void attn_k(
    const u16* __restrict__ proj,
    const u16* __restrict__ biasbf,
    const void* __restrict__ mask,
    const int* __restrict__ key_idx,
    u16* __restrict__ o_out,
    const int* __restrict__ dtf)
{
    __shared__ __align__(16) u16 Ks[128][136];
    __shared__ __align__(16) u16 Vt[128][136];
    const int tid = threadIdx.x;
    const int b = blockIdx.x >> 9, w = blockIdx.x & 511;
    int raw = key_idx[w * 128];
    if ((unsigned)raw > (unsigned)(N_ - H_))
        raw = (int)__builtin_bit_cast(float, raw);
    const int ks0 = raw < 0 ? 0 : (raw > N_ - H_ ? N_ - H_ : raw);
    const int lane = tid & 63, h = tid >> 6;
    const int lr = lane & 15, lq = lane >> 4;
    const int hoff = h * 32;
    const int f = dtf[0];

#pragma unroll
    for (int i = 0; i < 8; ++i) {
        int id = tid + i * 256;
        int r = id >> 4, c = (id & 15) * 8;
        size_t gbase = ((size_t)(b * N_ + ks0 + r)) * 512;
        *(u16x8*)&Ks[r][c] = *(const u16x8*)&proj[gbase + 128 + c];
        u16x8 v = *(const u16x8*)&proj[gbase + 256 + c];
#pragma unroll
        for (int j = 0; j < 8; ++j) {
            int d = c + j;
            Vt[d][r ^ VSWZ(d)] = v[j];
        }
    }
    __syncthreads();

    bf16x8 aq[2];
#pragma unroll
    for (int mt = 0; mt < 2; ++mt) {
        int qa = w * 32 + mt * 16 + lr;
        aq[mt] = *(const bf16x8*)&proj[((size_t)(b * N_ + qa)) * 512 + hoff + lq * 8];
    }
    f32x4 zero4 = {0.f, 0.f, 0.f, 0.f};
    f32x4 s[2][8];
#pragma unroll
    for (int nt = 0; nt < 8; ++nt) {
        bf16x8 bk = *(const bf16x8*)&Ks[nt * 16 + lr][hoff + lq * 8];
        s[0][nt] = __builtin_amdgcn_mfma_f32_16x16x32_bf16(aq[0], bk, zero4, 0, 0, 0);
        s[1][nt] = __builtin_amdgcn_mfma_f32_16x16x32_bf16(aq[1], bk, zero4, 0, 0, 0);
    }

    const float scl = 0.17677669529663687f;
    float mb[8];
#pragma unroll
    for (int nt = 0; nt < 8; ++nt)
        mb[nt] = (1.f - ldin(mask, (size_t)b * N_ + ks0 + nt * 16 + lr, f)) * -1e9f;
    size_t bb = (((size_t)b * 512 + w) * 4 + h) * (size_t)(32 * 128);
#pragma unroll
    for (int mt = 0; mt < 2; ++mt)
#pragma unroll
        for (int nt = 0; nt < 8; ++nt)
#pragma unroll
            for (int r = 0; r < 4; ++r) {
                int qq = mt * 16 + lq * 4 + r;
                int kk = nt * 16 + lr;
                s[mt][nt][r] = s[mt][nt][r] * scl + b2f(biasbf[bb + qq * 128 + kk]) + mb[nt];
            }

#pragma unroll
    for (int mt = 0; mt < 2; ++mt)
#pragma unroll
        for (int r = 0; r < 4; ++r) {
            float mx = -3.4e38f;
#pragma unroll
            for (int nt = 0; nt < 8; ++nt) mx = fmaxf(mx, s[mt][nt][r]);
#pragma unroll
            for (int off = 1; off < 16; off <<= 1) mx = fmaxf(mx, __shfl_xor(mx, off, 64));
            float sm = 0.f;
#pragma unroll
            for (int nt = 0; nt < 8; ++nt) {
                float p = __expf(s[mt][nt][r] - mx);
                s[mt][nt][r] = p; sm += p;
            }
#pragma unroll
            for (int off = 1; off < 16; off <<= 1) sm += __shfl_xor(sm, off, 64);
            float inv = 1.f / sm;
#pragma unroll
            for (int nt = 0; nt < 8; ++nt) s[mt][nt][r] *= inv;
        }

    __syncthreads();
#pragma unroll
    for (int mt = 0; mt < 2; ++mt)
#pragma unroll
        for (int nt = 0; nt < 8; ++nt)
#pragma unroll
            for (int r = 0; r < 4; ++r)
                Ks[hoff + mt * 16 + lq * 4 + r][nt * 16 + lr] = f2b(s[mt][nt][r]);
    __syncthreads();

    f32x4 o[2][2];
    o[0][0] = zero4; o[0][1] = zero4; o[1][0] = zero4; o[1][1] = zero4;
#pragma unroll
    for (int kst = 0; kst < 4; ++kst) {
        bf16x8 ap[2], bv[2];
#pragma unroll
        for (int mt = 0; mt < 2; ++mt)
            ap[mt] = *(const bf16x8*)&Ks[hoff + mt * 16 + lr][kst * 32 + lq * 8];
#pragma unroll
        for (int nt = 0; nt < 2; ++nt) {
            int d = hoff + nt * 16 + lr;
            bv[nt] = *(const bf16x8*)&Vt[d][(kst * 32 + lq * 8) ^ VSWZ(d)];
        }
#pragma unroll
        for (int mt = 0; mt < 2; ++mt)
#pragma unroll
            for (int nt = 0; nt < 2; ++nt)
                o[mt][nt] = __builtin_amdgcn_mfma_f32_16x16x32_bf16(ap[mt], bv[nt], o[mt][nt], 0, 0, 0);
    }

#pragma unroll
    for (int mt = 0; mt < 2; ++mt)
#pragma unroll
        for (int nt = 0; nt < 2; ++nt)
#pragma unroll
            for (int r = 0; r < 4; ++r) {
                int qa = w * 32 + mt * 16 + lq * 4 + r;
                int d = hoff + nt * 16 + lr;
                size_t gi = ((size_t)(b * N_ + qa)) * 512 + 384 + d;
                float g = sigf(b2f(proj[gi]));
                o_out[((size_t)(b * N_ + qa)) * 128 + d] = f2b(g * o[mt][nt][r]);
            }
}

// ---------------------------------------------------------------------------
// Merged prologue (R10: bias->bf16 copy phase RESTORED): blocks [0,8192)
// bias->bf16; [8192,16384) LN(c)->cn; [16384,16384+43*12) weight transposes,
// 64x64 LDS-tiled. TJob.ilv!=0 writes interleaved output rows (W1/W2).
// ---------------------------------------------------------------------------
struct TJob { const void* base; int off; int dst; int K; int N; int ilv; };
struct TJobs { TJob j[43]; };
__global__ __launch_bounds__(256) void prologue_k(
    const void* __restrict__ bias_in, u16* __restrict__ biasbf,
    const void* __restrict__ c_in, u16* __restrict__ cn,
    TJobs jobs, u16* __restrict__ wt, const int* __restrict__ dtf)
{
    __shared__ __align__(16) u16 Ls[64][72];   // 72-pitch keeps u16x8 stores 16B-aligned
    int bx = blockIdx.x;
    int f = dtf[0];
    if (bx < 8192) {
        size_t i = ((size_t)bx * 256 + threadIdx.x) * 8;
        if (f) {
            const float* s = (const float*)bias_in;
            f32x4 p0 = *(const f32x4*)&s[i];
            f32x4 p1 = *(const f32x4*)&s[i + 4];
            u16x8 t;
            t[0] = f2b(p0[0]); t[1] = f2b(p0[1]); t[2] = f2b(p0[2]); t[3] = f2b(p0[3]);
            t[4] = f2b(p1[0]); t[5] = f2b(p1[1]); t[6] = f2b(p1[2]); t[7] = f2b(p1[3]);
            *(u16x8*)&biasbf[i] = t;
        } else {
            *(u16x8*)&biasbf[i] = *(const u16x8*)&((const u16*)bias_in)[i];
        }
    } else if (bx < 16384) {
        int row = (bx - 8192) * 4 + (threadIdx.x >> 6);
        int l = threadIdx.x & 63;
        size_t base = (size_t)row * 128;
        float a = ldin(c_in, base + l, f), b = ldin(c_in, base + l + 64, f);
        float s = a + b, ss = a * a + b * b;
#pragma unroll
        for (int off = 1; off < 64; off <<= 1) {
            s  += __shfl_xor(s, off, 64);
            ss += __shfl_xor(ss, off, 64);
        }
        float m = s * (1.f / 128.f);
        float v = ss * (1.f / 128.f) - m * m;
        float inv = rsqrtf(fmaxf(v, 0.f) + 1e-5f);
        cn[base + l]      = f2b((a - m) * inv);
        cn[base + l + 64] = f2b((b - m) * inv);
    } else {
        int t = bx - 16384;
        int jidx = t / 12, tidx = t - jidx * 12;
        TJob jb = jobs.j[jidx];
        int ntk = jb.K >> 6, ntn = jb.N >> 6;       // 64x64 tiles
        if (tidx >= ntk * ntn) return;
        int kt = (tidx % ntk) << 6;
        int nt = (tidx / ntk) << 6;
        int r = threadIdx.x >> 3, cc = (threadIdx.x & 7) * 8;
#pragma unroll
        for (int p = 0; p < 2; ++p) {
            int kl = r + p * 32;
            size_t si = (size_t)jb.off + (size_t)(kt + kl) * jb.N + nt + cc;
            u16x8 v;
            if (f) {
                const float* s = (const float*)jb.base;
                f32x4 p0 = *(const f32x4*)&s[si];
                f32x4 p1 = *(const f32x4*)&s[si + 4];
                v[0] = f2b(p0[0]); v[1] = f2b(p0[1]); v[2] = f2b(p0[2]); v[3] = f2b(p0[3]);
                v[4] = f2b(p1[0]); v[5] = f2b(p1[1]); v[6] = f2b(p1[2]); v[7] = f2b(p1[3]);
            } else {
                v = *(const u16x8*)&((const u16*)jb.base)[si];
            }
            *(u16x8*)&Ls[kl][cc] = v;
        }
        __syncthreads();
#pragma unroll
        for (int p = 0; p < 2; ++p) {
            int nl = r + p * 32;
            u16x8 w;
#pragma unroll
            for (int j = 0; j < 8; ++j) w[j] = Ls[cc + j][nl];
            int fcol = nt + nl;
            size_t orow = jb.ilv
                ? (size_t)(((fcol >> 6) << 7) + ((fcol & 63) << 1) + (jb.ilv - 1))
                : (size_t)fcol;
            *(u16x8*)&wt[(size_t)jb.dst + orow * jb.K + kt + cc] = w;
        }
    }
}

// ---------------------------------------------------------------------------
// initq + first LN-mix: qf = q_in + aw[token]; hcur = LN(qf)*cs0 + cb0.
// ---------------------------------------------------------------------------
__global__ __launch_bounds__(256) void initq_ln_k(
    const void* __restrict__ qin, const float* __restrict__ aw,
    float* __restrict__ qf,
    const u16* __restrict__ cs0, const u16* __restrict__ cb0, int sgcbld,
    u16* __restrict__ hcur, const int* __restrict__ dtf)
{
    int an = blockIdx.x * 4 + (threadIdx.x >> 6);
    int l = threadIdx.x & 63;
    int f = dtf[0];
    int b = an >> 14, n = an & 16383, t = n >> 3;
    size_t base = (size_t)an * 128;
    size_t ab = ((size_t)b * T_ + t) * 128;
    float a0 = ldin(qin, base + l, f)      + aw[ab + l];
    float a1 = ldin(qin, base + l + 64, f) + aw[ab + l + 64];
    qf[base + l] = a0; qf[base + l + 64] = a1;
    float s = a0 + a1, ss = a0 * a0 + a1 * a1;
#pragma unroll
    for (int off = 1; off < 64; off <<= 1) {
        s  += __shfl_xor(s, off, 64);
        ss += __shfl_xor(ss, off, 64);
    }
    float m = s * (1.f / 128.f);
    float v = ss * (1.f / 128.f) - m * m;
    float inv = rsqrtf(fmaxf(v, 0.f) + 1e-5f);
    size_t sb = (size_t)an * sgcbld;
    hcur[base + l]      = f2b((a0 - m) * inv * b2f(cs0[sb + l])      + b2f(cb0[sb + l]));
    hcur[base + l + 64] = f2b((a1 - m) * inv * b2f(cs0[sb + l + 64]) + b2f(cb0[sb + l + 64]));
}

// ---------------------------------------------------------------------------
// Merged finals: blocks [0,8192) r_update; [8192,9216) res_type (wave/token).
// ---------------------------------------------------------------------------
__global__ __launch_bounds__(256) void final_k(const float* __restrict__ q,
    const void* __restrict__ ln_g, const void* __restrict__ ln_b,
    const void* __restrict__ Wpos,
    const void* __restrict__ mask, const void* __restrict__ Wres,
    const void* __restrict__ bres,
    float* __restrict__ out1, float* __restrict__ out2,
    const int* __restrict__ dtf)
{
    int f = dtf[0];
    int bx = blockIdx.x;
    if (bx < 8192) {
        int row = bx * 4 + (threadIdx.x >> 6);
        int l = threadIdx.x & 63;
        size_t base = (size_t)row * 128;
        float a = q[base + l], b = q[base + l + 64];
        float s = a + b, ss = a * a + b * b;
#pragma unroll
        for (int off = 1; off < 64; off <<= 1) {
            s  += __shfl_xor(s, off, 64);
            ss += __shfl_xor(ss, off, 64);
        }
        float m = s * (1.f / 128.f);
        float v = ss * (1.f / 128.f) - m * m;
        float inv = rsqrtf(fmaxf(v, 0.f) + 1e-5f);
        float y0 = (a - m) * inv * ldin(ln_g, l, f)      + ldin(ln_b, l, f);
        float y1 = (b - m) * inv * ldin(ln_g, l + 64, f) + ldin(ln_b, l + 64, f);
        float p0 = y0 * ldin(Wpos, l * 3 + 0, f) + y1 * ldin(Wpos, (l + 64) * 3 + 0, f);
        float p1 = y0 * ldin(Wpos, l * 3 + 1, f) + y1 * ldin(Wpos, (l + 64) * 3 + 1, f);
        float p2 = y0 * ldin(Wpos, l * 3 + 2, f) + y1 * ldin(Wpos, (l + 64) * 3 + 2, f);
#pragma unroll
        for (int off = 1; off < 64; off <<= 1) {
            p0 += __shfl_xor(p0, off, 64);
            p1 += __shfl_xor(p1, off, 64);
            p2 += __shfl_xor(p2, off, 64);
        }
        if (l == 0) {
            out1[(size_t)row * 3 + 0] = p0;
            out1[(size_t)row * 3 + 1] = p1;
            out1[(size_t)row * 3 + 2] = p2;
        }
    } else {
        __shared__ float sfeat[4][128];
        int wid = threadIdx.x >> 6, l = threadIdx.x & 63;
        int tok = (bx - 8192) * 4 + wid;
        int b = tok >> 11, t = tok & 2047;
        float a0 = 0.f, a1 = 0.f;
#pragma unroll
        for (int i = 0; i < 8; ++i) {
            size_t an = (size_t)b * N_ + t * 8 + i;
            float mk = ldin(mask, an, f);
            a0 += q[an * 128 + l] * mk;
            a1 += q[an * 128 + l + 64] * mk;
        }
        sfeat[wid][l] = a0; sfeat[wid][l + 64] = a1;
        __builtin_amdgcn_s_waitcnt(0);  // wave-local LDS visibility
        if (l < NTOK_) {
            float r = ldin(bres, l, f);
            for (int d = 0; d < 128; ++d) r += sfeat[wid][d] * ldin(Wres, d * NTOK_ + l, f);
            out2[(size_t)tok * NTOK_ + l] = r;
        }
    }
}

// ---------------------------------------------------------------------------
// Workspace layout (bytes), ws = 1 GiB:
//   wt      : 0           weight arena (flag int at 2,088,960)
//   qf      : 2,097,152    f32 BN x 128
//   cn      : 18,874,368   bf16
//   biasbf  : 27,262,976   bf16 (33.5 MB)
//   cnprojS : 60,817,408   bf16 BN x 256 [cb0 | cs0]
//   hcur    : 211,812,352  bf16 (layer-0 attn input only)
//   proj    : 220,200,960  bf16 BN x 512
//   obuf    : 253,755,392  bf16
//   aw      : 262,144,000  f32 (prologue only)
// ---------------------------------------------------------------------------
extern "C" void kernel_launch(void* const* d_in, const int* in_sizes, int n_in,
                              void* d_out, int out_size, void* d_ws, size_t ws_size,
                              hipStream_t stream)
{
    (void)out_size;
    float* out = (float*)d_out;
    const size_t WS_NEED = 295698432;

    static const int EXP_SZ[27] = {
        1572864, 4194304, 4194304, 16777216, 67108864, 32768, 65536,
        49152, 49152, 49152, 49152, 49152, 49152,
        49152, 49152, 49152, 49152, 49152, 49152,
        98304, 98304, 98304, 128, 128, 384, 4224, 33 };
    int bad = -1;
    int ncheck = n_in < 27 ? n_in : 27;
    for (int i = 0; i < ncheck; ++i)
        if (in_sizes[i] != EXP_SZ[i]) { bad = i; break; }
    if (bad >= 0) { sentinel_k<<<1, 64, 0, stream>>>(out, 256.0f * (bad + 1)); return; }
    if (n_in < 27) { sentinel_k<<<1, 64, 0, stream>>>(out, 8192.0f); return; }
    if (ws_size < WS_NEED) { sentinel_k<<<1, 64, 0, stream>>>(out, 12288.0f); return; }

    const void* a_in    = d_in[0];
    const void* q_in    = d_in[1];
    const void* c_in    = d_in[2];
    const void* bias_in = d_in[3];
    const void* mask_in = d_in[5];
    const int*  kidx    = (const int*)d_in[6];
    const void* a2q  = d_in[7];
    const void* Wq   = d_in[8];
    const void* Wk   = d_in[9];
    const void* Wv   = d_in[10];
    const void* Wg   = d_in[11];
    const void* Wo   = d_in[12];
    const void* Wcs  = d_in[13];
    const void* Wcb  = d_in[14];
    const void* Wog  = d_in[15];
    const void* Wcs2 = d_in[16];
    const void* Wcb2 = d_in[17];
    const void* Wog2 = d_in[18];
    const void* W1   = d_in[19];
    const void* W2   = d_in[20];
    const void* W3   = d_in[21];
    const void* ln_g = d_in[22];
    const void* ln_b = d_in[23];
    const void* Wpos = d_in[24];
    const void* Wres = d_in[25];
    const void* bres = d_in[26];

    char* ws = (char*)d_ws;
    u16*   wt      = (u16*)ws;
    int*   flag    = (int*)(ws + 2088960);
    float* qf      = (float*)(ws + 2097152);
    u16*   cn      = (u16*)(ws + 18874368);
    u16*   biasbf  = (u16*)(ws + 27262976);
    u16*   cnprojS = (u16*)(ws + 60817408);
    u16*   hcur    = (u16*)(ws + 211812352);
    u16*   proj    = (u16*)(ws + 220200960);
    u16*   obuf    = (u16*)(ws + 253755392);
    float* aw      = (float*)(ws + 262144000);

    detect_k<<<1, 64, 0, stream>>>((const u16*)a_in, flag);

    // weight arena (elements):
    //   0..196608       Wq|Wk|Wv|Wg per layer (l*65536)
    //   196608 cb0 | 212992 cs0
    //   229376 og[l] | 278528 cs2[l] | 327680 cb2[l] | 376832 og2[l]
    //   425984 cs[1],cs[2] | 458752 cb[1],cb[2]
    //   491520 w12 INTERLEAVED arena | 688128 W3 | 786432 a2q | 835584 Wo
    TJobs jobs; int nj = 0;
    for (int l = 0; l < 3; ++l) {
        jobs.j[nj++] = {Wq,   l * 16384, l * 65536 + 0,     128, 128, 0};
        jobs.j[nj++] = {Wk,   l * 16384, l * 65536 + 16384, 128, 128, 0};
        jobs.j[nj++] = {Wv,   l * 16384, l * 65536 + 32768, 128, 128, 0};
        jobs.j[nj++] = {Wg,   l * 16384, l * 65536 + 49152, 128, 128, 0};
        jobs.j[nj++] = {Wog,  l * 16384, 229376 + l * 16384, 128, 128, 0};
        jobs.j[nj++] = {Wcs2, l * 16384, 278528 + l * 16384, 128, 128, 0};
        jobs.j[nj++] = {Wcb2, l * 16384, 327680 + l * 16384, 128, 128, 0};
        jobs.j[nj++] = {Wog2, l * 16384, 376832 + l * 16384, 128, 128, 0};
        jobs.j[nj++] = {W1,   l * 32768, 491520 + l * 65536, 128, 256, 1};
        jobs.j[nj++] = {W2,   l * 32768, 491520 + l * 65536, 128, 256, 2};
        jobs.j[nj++] = {W3,   l * 32768, 688128 + l * 32768, 256, 128, 0};
        jobs.j[nj++] = {Wo,   l * 16384, 835584 + l * 16384, 128, 128, 0};
    }
    jobs.j[nj++] = {Wcb, 0,     196608, 128, 128, 0};
    jobs.j[nj++] = {Wcs, 0,     212992, 128, 128, 0};
    jobs.j[nj++] = {Wcs, 16384, 425984, 128, 128, 0};
    jobs.j[nj++] = {Wcs, 32768, 442368, 128, 128, 0};
    jobs.j[nj++] = {Wcb, 16384, 458752, 128, 128, 0};
    jobs.j[nj++] = {Wcb, 32768, 475136, 128, 128, 0};
    jobs.j[nj++] = {a2q, 0,     786432, 384, 128, 0};

    prologue_k<<<16384 + 43 * 12, 256, 0, stream>>>(bias_in, biasbf, c_in, cn, jobs, wt, flag);
    // aw = a @ a2q (M=4096, K=384, asrc=1)
    gemm_k<<<dim3(32, 1), 256, 0, stream>>>(
        (const u16*)a_in, S_, 1, wt + 786432, S_, nullptr, D_, aw, M_F32, flag);
    // cnprojS = [cb0 | sig(cs0)]
    gemm_k<<<dim3(256, 2), 256, 0, stream>>>(
        cn, D_, 0, wt + 196608, D_, cnprojS, 256, nullptr, M_CBSG, nullptr);
    // qf init + layer-0 attention-half hcur
    initq_ln_k<<<8192, 256, 0, stream>>>(q_in, aw, qf,
        cnprojS + 128, cnprojS + 0, 256, hcur, flag);

    // layer-0 attention projections
    gemm_k<<<dim3(256, 4), 256, 0, stream>>>(
        hcur, D_, 0, wt + 0, D_, proj, 512, nullptr, M_STORE, nullptr);

    for (int l = 0; l < 3; ++l) {
        const u16* wt_proj_n = wt + (l + 1) * 65536;
        const u16* wt_w12  = wt + 491520 + l * 65536;
        const u16* wt_w3   = wt + 688128 + l * 32768;
        const u16* wt_wo   = wt + 835584 + l * 16384;
        const u16* wt_og   = wt + 229376 + l * 16384;
        const u16* wt_cs2  = wt + 278528 + l * 16384;
        const u16* wt_cb2  = wt + 327680 + l * 16384;
        const u16* wt_og2  = wt + 376832 + l * 16384;
        const u16* wt_cs_n = wt + 425984 + l * 16384;   // Wcs[l+1] (l<2)
        const u16* wt_cb_n = wt + 458752 + l * 16384;   // Wcb[l+1] (l<2)

        attn_k<<<1024, 256, 0, stream>>>(proj, biasbf, mask_in, kidx, obuf, flag);
        // one merged kernel per layer: Wo-residual + LN + FFN (u12 in LDS) +
        // W3-residual + LN + next-layer proj
        fres_k<<<256, 256, 0, stream>>>(
            obuf, cn, wt_wo, wt_og, wt_cs2, wt_cb2,
            wt_w12, wt_w3, wt_og2,
            l < 2 ? wt_cs_n : nullptr, l < 2 ? wt_cb_n : nullptr,
            qf,
            l < 2 ? wt_proj_n : nullptr, proj, l == 2 ? 1 : 0);
    }

    final_k<<<9216, 256, 0, stream>>>(qf, ln_g, ln_b, Wpos, mask_in, Wres, bres,
                                      out, out + (size_t)BN_ * 3, flag);
}